// Round 1
// baseline (1800.800 us; speedup 1.0000x reference)
//
#include <hip/hip_runtime.h>

// Problem constants (from reference)
#define NFEAT 128
#define HID   128
#define H3    64
#define NGRAPH 100

// ---------------- degree / norm ----------------

__global__ void deg_kernel(const int* __restrict__ col, float* __restrict__ deg, int E) {
    int e = blockIdx.x * blockDim.x + threadIdx.x;
    if (e < E) atomicAdd(&deg[col[e]], 1.0f);
}

__global__ void dinv_kernel(float* __restrict__ deg, int n) {
    int i = blockIdx.x * blockDim.x + threadIdx.x;
    if (i < n) {
        float d = deg[i] + 1.0f;           // +1 self-loop; always > 0
        deg[i] = 1.0f / sqrtf(d);          // in-place: deg becomes dinv
    }
}

// ---------------- GEMM: Y[n,OUT] = transform(X[n,128]) @ W[128,OUT] ----------------
// transform(v,k) = bias_in ? relu(v + bias_in[k]) : v   (fuses prev layer's bias+relu)

template <int OUT>
__global__ void gemm_kernel(const float* __restrict__ X, const float* __restrict__ W,
                            const float* __restrict__ bias_in, float* __restrict__ Y,
                            int n) {
    constexpr int CG  = OUT / 4;      // column groups of 4
    constexpr int RPB = 256 / CG;     // rows per block-iteration (8 or 16)
    __shared__ float Ws[128 * OUT];
    __shared__ float xs[RPB * 128];
    __shared__ float bs[128];

    const int t = threadIdx.x;
    // stage W into LDS (vectorized)
    for (int i = t * 4; i < 128 * OUT; i += 256 * 4)
        *(float4*)&Ws[i] = *(const float4*)&W[i];
    if (t < 128) bs[t] = (bias_in != nullptr) ? bias_in[t] : 0.0f;
    __syncthreads();

    const int cg = t % CG;
    const int rg = t / CG;
    const bool do_relu = (bias_in != nullptr);

    for (int row0 = blockIdx.x * RPB; row0 < n; row0 += gridDim.x * RPB) {
        // stage RPB input rows (with fused bias+relu transform)
        for (int i = t; i < RPB * 32; i += 256) {
            int r  = i / 32;
            int cc = (i % 32) * 4;
            int gr = row0 + r;
            float4 v = make_float4(0.f, 0.f, 0.f, 0.f);
            if (gr < n) v = *(const float4*)&X[(size_t)gr * 128 + cc];
            if (do_relu) {
                v.x = fmaxf(v.x + bs[cc + 0], 0.f);
                v.y = fmaxf(v.y + bs[cc + 1], 0.f);
                v.z = fmaxf(v.z + bs[cc + 2], 0.f);
                v.w = fmaxf(v.w + bs[cc + 3], 0.f);
            }
            *(float4*)&xs[r * 128 + cc] = v;
        }
        __syncthreads();

        int gr = row0 + rg;
        if (gr < n) {
            float4 acc = make_float4(0.f, 0.f, 0.f, 0.f);
            #pragma unroll
            for (int k = 0; k < 128; k += 4) {
                float4 xv = *(const float4*)&xs[rg * 128 + k];
                float4 w0 = *(const float4*)&Ws[(k + 0) * OUT + cg * 4];
                float4 w1 = *(const float4*)&Ws[(k + 1) * OUT + cg * 4];
                float4 w2 = *(const float4*)&Ws[(k + 2) * OUT + cg * 4];
                float4 w3 = *(const float4*)&Ws[(k + 3) * OUT + cg * 4];
                acc.x += xv.x * w0.x; acc.y += xv.x * w0.y; acc.z += xv.x * w0.z; acc.w += xv.x * w0.w;
                acc.x += xv.y * w1.x; acc.y += xv.y * w1.y; acc.z += xv.y * w1.z; acc.w += xv.y * w1.w;
                acc.x += xv.z * w2.x; acc.y += xv.z * w2.y; acc.z += xv.z * w2.z; acc.w += xv.z * w2.w;
                acc.x += xv.w * w3.x; acc.y += xv.w * w3.y; acc.z += xv.w * w3.z; acc.w += xv.w * w3.w;
            }
            *(float4*)&Y[(size_t)gr * OUT + cg * 4] = acc;
        }
        __syncthreads();
    }
}

// ---------------- self-loop init: out[i,:] = h[i,:] * dinv[i]^2 ----------------

template <int F>
__global__ void selfloop_init(const float* __restrict__ h, const float* __restrict__ dinv,
                              float* __restrict__ out, int n) {
    int idx = blockIdx.x * blockDim.x + threadIdx.x;    // float4 index
    int total = n * (F / 4);
    if (idx >= total) return;
    int node = idx / (F / 4);
    float w = dinv[node]; w *= w;
    float4 v = ((const float4*)h)[idx];
    v.x *= w; v.y *= w; v.z *= w; v.w *= w;
    ((float4*)out)[idx] = v;
}

// ---------------- edge scatter: out[col,:] += h[row,:] * dinv[row]*dinv[col] ----------------
// one wavefront per edge

template <int F>
__global__ void scatter_kernel(const float* __restrict__ h, float* __restrict__ out,
                               const int* __restrict__ row, const int* __restrict__ col,
                               const float* __restrict__ dinv, int E) {
    int lane = threadIdx.x & 63;
    int wave = (blockIdx.x * blockDim.x + threadIdx.x) >> 6;
    int nwav = (gridDim.x * blockDim.x) >> 6;
    for (int e = wave; e < E; e += nwav) {
        int r = row[e], c = col[e];
        float w = dinv[r] * dinv[c];
        if (F == 128) {
            float2 v = *(const float2*)&h[(size_t)r * 128 + lane * 2];
            atomicAdd(&out[(size_t)c * 128 + lane * 2 + 0], v.x * w);
            atomicAdd(&out[(size_t)c * 128 + lane * 2 + 1], v.y * w);
        } else {
            float v = h[(size_t)r * 64 + lane];
            atomicAdd(&out[(size_t)c * 64 + lane], v * w);
        }
    }
}

// ---------------- fused mean-pool + MLP head ----------------
// h3 is pre-bias/pre-relu scatter output; apply relu(h3 + b3) here.

__global__ void pool_mlp_kernel(const float* __restrict__ h, const float* __restrict__ b3,
                                const int* __restrict__ batch,
                                const float* __restrict__ Wf1, const float* __restrict__ bf1,
                                const float* __restrict__ Wf2, const float* __restrict__ bf2,
                                float* __restrict__ out, int n) {
    const int g = blockIdx.x;
    const int t = threadIdx.x;

    // lower_bound over sorted batch (redundant per-thread, 16 steps, cheap)
    auto lb = [&](int v) {
        int lo = 0, hi = n;
        while (lo < hi) { int mid = (lo + hi) >> 1; if (batch[mid] < v) lo = mid + 1; else hi = mid; }
        return lo;
    };
    const int start = lb(g);
    const int end   = lb(g + 1);

    __shared__ float part[4][64];
    __shared__ float pooled[64];
    __shared__ float hid[32];

    const int f = t & 63, sub = t >> 6;
    const float bias = b3[f];
    float acc = 0.f;
    for (int i = start + sub; i < end; i += 4)
        acc += fmaxf(h[(size_t)i * 64 + f] + bias, 0.f);
    part[sub][f] = acc;
    __syncthreads();

    if (t < 64) {
        float s = part[0][t] + part[1][t] + part[2][t] + part[3][t];
        int cnt = end - start;
        pooled[t] = s / (float)(cnt > 0 ? cnt : 1);
    }
    __syncthreads();

    if (t < 32) {
        float a = bf1[t];
        #pragma unroll
        for (int k = 0; k < 64; ++k) a += pooled[k] * Wf1[k * 32 + t];
        hid[t] = fmaxf(a, 0.f);
    }
    __syncthreads();

    if (t < 10) {
        float a = bf2[t];
        #pragma unroll
        for (int k = 0; k < 32; ++k) a += hid[k] * Wf2[k * 10 + t];
        out[g * 10 + t] = a;
    }
}

// ---------------- launcher ----------------

extern "C" void kernel_launch(void* const* d_in, const int* in_sizes, int n_in,
                              void* d_out, int out_size, void* d_ws, size_t ws_size,
                              hipStream_t stream) {
    const float* x     = (const float*)d_in[0];
    const int*   edge  = (const int*)  d_in[1];
    const int*   batch = (const int*)  d_in[2];
    const float* W1    = (const float*)d_in[3];
    const float* b1    = (const float*)d_in[4];
    const float* W2    = (const float*)d_in[5];
    const float* b2    = (const float*)d_in[6];
    const float* W3    = (const float*)d_in[7];
    const float* b3    = (const float*)d_in[8];
    const float* Wf1   = (const float*)d_in[9];
    const float* bf1   = (const float*)d_in[10];
    const float* Wf2   = (const float*)d_in[11];
    const float* bf2   = (const float*)d_in[12];
    float* out = (float*)d_out;

    const int E = in_sizes[1] / 2;     // 800000
    const int n = in_sizes[2];         // 50000
    const int* row = edge;
    const int* col = edge + E;

    float* ws   = (float*)d_ws;
    float* dinv = ws;                                   // n floats (deg -> dinv in place)
    size_t off  = ((size_t)n + 63) & ~(size_t)63;
    float* bufA = ws + off;                             // n*128 floats
    float* bufB = bufA + (size_t)n * 128;               // n*128 floats

    // degrees -> dinv
    hipMemsetAsync(dinv, 0, (size_t)n * sizeof(float), stream);
    deg_kernel<<<(E + 255) / 256, 256, 0, stream>>>(col, dinv, E);
    dinv_kernel<<<(n + 255) / 256, 256, 0, stream>>>(dinv, n);

    const int gemm_grid = 1024;
    const int scat_grid = 2048;

    // layer 1: A = x @ W1 ; B = selfloop + scatter
    gemm_kernel<128><<<gemm_grid, 256, 0, stream>>>(x, W1, nullptr, bufA, n);
    selfloop_init<128><<<(n * 32 + 255) / 256, 256, 0, stream>>>(bufA, dinv, bufB, n);
    scatter_kernel<128><<<scat_grid, 256, 0, stream>>>(bufA, bufB, row, col, dinv, E);

    // layer 2: A = relu(B + b1) @ W2 ; B = selfloop + scatter
    gemm_kernel<128><<<gemm_grid, 256, 0, stream>>>(bufB, W2, b1, bufA, n);
    selfloop_init<128><<<(n * 32 + 255) / 256, 256, 0, stream>>>(bufA, dinv, bufB, n);
    scatter_kernel<128><<<scat_grid, 256, 0, stream>>>(bufA, bufB, row, col, dinv, E);

    // layer 3 (64-wide): A = relu(B + b2) @ W3 ; B = selfloop + scatter
    gemm_kernel<64><<<gemm_grid, 256, 0, stream>>>(bufB, W3, b2, bufA, n);
    selfloop_init<64><<<(n * 16 + 255) / 256, 256, 0, stream>>>(bufA, dinv, bufB, n);
    scatter_kernel<64><<<scat_grid, 256, 0, stream>>>(bufA, bufB, row, col, dinv, E);

    // fused relu(+b3) -> mean pool -> MLP
    pool_mlp_kernel<<<NGRAPH, 256, 0, stream>>>(bufB, b3, batch, Wf1, bf1, Wf2, bf2, out, n);
}

// Round 2
// 557.499 us; speedup vs baseline: 3.2301x; 3.2301x over previous
//
#include <hip/hip_runtime.h>

// GCN: 3x (GEMM -> normalized adjacency aggregate) + mean-pool + MLP.
// R2: atomic scatter replaced by CSR build + per-node gather (no float atomics).
//   out[c] = dinv[c] * ( hs[c] + sum_{(r->c)} hs[r] ),  hs = (X@W) * dinv[row]
// dinv scale fused into GEMM epilogue; self-loop fused into gather init.

#define NGRAPH 100

// ---------------- degree histogram (int) ----------------

__global__ void deg_kernel(const int* __restrict__ col, int* __restrict__ cnt, int E) {
    int e = blockIdx.x * blockDim.x + threadIdx.x;
    if (e < E) atomicAdd(&cnt[col[e]], 1);
}

__global__ void dinv_kernel(const int* __restrict__ cnt, float* __restrict__ dinv, int n) {
    int i = blockIdx.x * blockDim.x + threadIdx.x;
    if (i < n) dinv[i] = 1.0f / sqrtf((float)(cnt[i] + 1));   // +1 self-loop
}

// ---------------- exclusive scan cnt[0..n) -> ptr[0..n], single block ----------------

__global__ __launch_bounds__(1024) void scan_kernel(const int* __restrict__ cnt,
                                                    int* __restrict__ ptr, int n, int E) {
    __shared__ int part[1024];
    const int t = threadIdx.x;
    const int chunk = (n + 1023) / 1024;
    const int beg = t * chunk;
    const int end = min(beg + chunk, n);
    int s = 0;
    for (int i = beg; i < end; ++i) s += cnt[i];
    part[t] = s;
    __syncthreads();
    for (int off = 1; off < 1024; off <<= 1) {
        int v = 0;
        if (t >= off) v = part[t - off];
        __syncthreads();
        if (t >= off) part[t] += v;
        __syncthreads();
    }
    int run = part[t] - s;   // exclusive prefix of this chunk
    for (int i = beg; i < end; ++i) { ptr[i] = run; run += cnt[i]; }
    if (t == 1023) ptr[n] = E;
}

// ---------------- CSR fill: csr[ptr[c] + cursor[c]++] = row[e] ----------------

__global__ void fill_kernel(const int* __restrict__ row, const int* __restrict__ col,
                            const int* __restrict__ ptr, int* __restrict__ cursor,
                            int* __restrict__ csr, int E) {
    int e = blockIdx.x * blockDim.x + threadIdx.x;
    if (e < E) {
        int c = col[e];
        int pos = atomicAdd(&cursor[c], 1);
        csr[ptr[c] + pos] = row[e];
    }
}

// ---------------- GEMM: Y[n,OUT] = transform(X[n,128]) @ W[128,OUT] * dinv[row] ----------
// transform(v,k) = bias_in ? relu(v + bias_in[k]) : v   (fuses prev layer's bias+relu)

template <int OUT>
__global__ void gemm_kernel(const float* __restrict__ X, const float* __restrict__ W,
                            const float* __restrict__ bias_in, const float* __restrict__ dinv,
                            float* __restrict__ Y, int n) {
    constexpr int CG  = OUT / 4;      // column groups of 4
    constexpr int RPB = 256 / CG;     // rows per block-iteration (8 or 16)
    __shared__ float Ws[128 * OUT];
    __shared__ float xs[RPB * 128];
    __shared__ float bs[128];

    const int t = threadIdx.x;
    for (int i = t * 4; i < 128 * OUT; i += 256 * 4)
        *(float4*)&Ws[i] = *(const float4*)&W[i];
    if (t < 128) bs[t] = (bias_in != nullptr) ? bias_in[t] : 0.0f;
    __syncthreads();

    const int cg = t % CG;
    const int rg = t / CG;
    const bool do_relu = (bias_in != nullptr);

    for (int row0 = blockIdx.x * RPB; row0 < n; row0 += gridDim.x * RPB) {
        for (int i = t; i < RPB * 32; i += 256) {
            int r  = i / 32;
            int cc = (i % 32) * 4;
            int gr = row0 + r;
            float4 v = make_float4(0.f, 0.f, 0.f, 0.f);
            if (gr < n) v = *(const float4*)&X[(size_t)gr * 128 + cc];
            if (do_relu) {
                v.x = fmaxf(v.x + bs[cc + 0], 0.f);
                v.y = fmaxf(v.y + bs[cc + 1], 0.f);
                v.z = fmaxf(v.z + bs[cc + 2], 0.f);
                v.w = fmaxf(v.w + bs[cc + 3], 0.f);
            }
            *(float4*)&xs[r * 128 + cc] = v;
        }
        __syncthreads();

        int gr = row0 + rg;
        if (gr < n) {
            float4 acc = make_float4(0.f, 0.f, 0.f, 0.f);
            #pragma unroll
            for (int k = 0; k < 128; k += 4) {
                float4 xv = *(const float4*)&xs[rg * 128 + k];
                float4 w0 = *(const float4*)&Ws[(k + 0) * OUT + cg * 4];
                float4 w1 = *(const float4*)&Ws[(k + 1) * OUT + cg * 4];
                float4 w2 = *(const float4*)&Ws[(k + 2) * OUT + cg * 4];
                float4 w3 = *(const float4*)&Ws[(k + 3) * OUT + cg * 4];
                acc.x += xv.x * w0.x; acc.y += xv.x * w0.y; acc.z += xv.x * w0.z; acc.w += xv.x * w0.w;
                acc.x += xv.y * w1.x; acc.y += xv.y * w1.y; acc.z += xv.y * w1.z; acc.w += xv.y * w1.w;
                acc.x += xv.z * w2.x; acc.y += xv.z * w2.y; acc.z += xv.z * w2.z; acc.w += xv.z * w2.w;
                acc.x += xv.w * w3.x; acc.y += xv.w * w3.y; acc.z += xv.w * w3.z; acc.w += xv.w * w3.w;
            }
            float dw = dinv[gr];
            acc.x *= dw; acc.y *= dw; acc.z *= dw; acc.w *= dw;
            *(float4*)&Y[(size_t)gr * OUT + cg * 4] = acc;
        }
        __syncthreads();
    }
}

// ---------------- gather: out[c,:] = dinv[c] * (hs[c,:] + sum_in hs[src,:]) ----------------
// one wave per destination node

template <int F>
__global__ void gather_kernel(const float* __restrict__ hs, const float* __restrict__ dinv,
                              const int* __restrict__ ptr, const int* __restrict__ csr,
                              float* __restrict__ out, int n) {
    const int lane = threadIdx.x & 63;
    const int c = (blockIdx.x * blockDim.x + threadIdx.x) >> 6;
    if (c >= n) return;
    const int beg = ptr[c], end = ptr[c + 1];
    const float w = dinv[c];

    if (F == 128) {
        const float2* h2 = (const float2*)hs;
        const size_t li = lane;
        float2 acc = h2[(size_t)c * 64 + li];            // self-loop
        int j = beg;
        for (; j + 4 <= end; j += 4) {
            int s0 = csr[j], s1 = csr[j + 1], s2 = csr[j + 2], s3 = csr[j + 3];
            float2 v0 = h2[(size_t)s0 * 64 + li];
            float2 v1 = h2[(size_t)s1 * 64 + li];
            float2 v2 = h2[(size_t)s2 * 64 + li];
            float2 v3 = h2[(size_t)s3 * 64 + li];
            acc.x += v0.x + v1.x + v2.x + v3.x;
            acc.y += v0.y + v1.y + v2.y + v3.y;
        }
        for (; j < end; ++j) {
            float2 v = h2[(size_t)csr[j] * 64 + li];
            acc.x += v.x; acc.y += v.y;
        }
        *(float2*)&out[(size_t)c * 128 + lane * 2] = make_float2(w * acc.x, w * acc.y);
    } else {     // F == 64
        float acc = hs[(size_t)c * 64 + lane];
        int j = beg;
        for (; j + 4 <= end; j += 4) {
            int s0 = csr[j], s1 = csr[j + 1], s2 = csr[j + 2], s3 = csr[j + 3];
            float v0 = hs[(size_t)s0 * 64 + lane];
            float v1 = hs[(size_t)s1 * 64 + lane];
            float v2 = hs[(size_t)s2 * 64 + lane];
            float v3 = hs[(size_t)s3 * 64 + lane];
            acc += v0 + v1 + v2 + v3;
        }
        for (; j < end; ++j) acc += hs[(size_t)csr[j] * 64 + lane];
        out[(size_t)c * 64 + lane] = w * acc;
    }
}

// ---------------- fused mean-pool + MLP head ----------------

__global__ void pool_mlp_kernel(const float* __restrict__ h, const float* __restrict__ b3,
                                const int* __restrict__ batch,
                                const float* __restrict__ Wf1, const float* __restrict__ bf1,
                                const float* __restrict__ Wf2, const float* __restrict__ bf2,
                                float* __restrict__ out, int n) {
    const int g = blockIdx.x;
    const int t = threadIdx.x;

    auto lb = [&](int v) {
        int lo = 0, hi = n;
        while (lo < hi) { int mid = (lo + hi) >> 1; if (batch[mid] < v) lo = mid + 1; else hi = mid; }
        return lo;
    };
    const int start = lb(g);
    const int end   = lb(g + 1);

    __shared__ float part[4][64];
    __shared__ float pooled[64];
    __shared__ float hid[32];

    const int f = t & 63, sub = t >> 6;
    const float bias = b3[f];
    float acc = 0.f;
    for (int i = start + sub; i < end; i += 4)
        acc += fmaxf(h[(size_t)i * 64 + f] + bias, 0.f);
    part[sub][f] = acc;
    __syncthreads();

    if (t < 64) {
        float s = part[0][t] + part[1][t] + part[2][t] + part[3][t];
        int cnt = end - start;
        pooled[t] = s / (float)(cnt > 0 ? cnt : 1);
    }
    __syncthreads();

    if (t < 32) {
        float a = bf1[t];
        #pragma unroll
        for (int k = 0; k < 64; ++k) a += pooled[k] * Wf1[k * 32 + t];
        hid[t] = fmaxf(a, 0.f);
    }
    __syncthreads();

    if (t < 10) {
        float a = bf2[t];
        #pragma unroll
        for (int k = 0; k < 32; ++k) a += hid[k] * Wf2[k * 10 + t];
        out[g * 10 + t] = a;
    }
}

// ---------------- launcher ----------------

extern "C" void kernel_launch(void* const* d_in, const int* in_sizes, int n_in,
                              void* d_out, int out_size, void* d_ws, size_t ws_size,
                              hipStream_t stream) {
    const float* x     = (const float*)d_in[0];
    const int*   edge  = (const int*)  d_in[1];
    const int*   batch = (const int*)  d_in[2];
    const float* W1    = (const float*)d_in[3];
    const float* b1    = (const float*)d_in[4];
    const float* W2    = (const float*)d_in[5];
    const float* b2    = (const float*)d_in[6];
    const float* W3    = (const float*)d_in[7];
    const float* b3    = (const float*)d_in[8];
    const float* Wf1   = (const float*)d_in[9];
    const float* bf1   = (const float*)d_in[10];
    const float* Wf2   = (const float*)d_in[11];
    const float* bf2   = (const float*)d_in[12];
    float* out = (float*)d_out;

    const int E = in_sizes[1] / 2;     // 800000
    const int n = in_sizes[2];         // 50000
    const int* row = edge;
    const int* col = edge + E;

    const size_t n_pad = ((size_t)n + 64) & ~(size_t)63;   // >= n+1, 64-aligned
    char* wsb = (char*)d_ws;
    int*   cnt   = (int*)wsb;                    wsb += n_pad * 4;   // also reused as cursor
    int*   ptr   = (int*)wsb;                    wsb += n_pad * 4;
    float* dinv  = (float*)wsb;                  wsb += n_pad * 4;
    int*   csr   = (int*)wsb;                    wsb += (((size_t)E + 63) & ~(size_t)63) * 4;
    float* bufA  = (float*)wsb;                  wsb += (size_t)n * 128 * 4;
    float* bufB  = (float*)wsb;

    // ---- CSR build (once, reused for all 3 layers) ----
    hipMemsetAsync(cnt, 0, (size_t)n * 4, stream);
    deg_kernel<<<(E + 255) / 256, 256, 0, stream>>>(col, cnt, E);
    dinv_kernel<<<(n + 255) / 256, 256, 0, stream>>>(cnt, dinv, n);
    scan_kernel<<<1, 1024, 0, stream>>>(cnt, ptr, n, E);
    hipMemsetAsync(cnt, 0, (size_t)n * 4, stream);         // cnt -> cursor
    fill_kernel<<<(E + 255) / 256, 256, 0, stream>>>(row, col, ptr, cnt, csr, E);

    const int gemm_grid = 1024;
    const int gath_grid = (n * 64 + 255) / 256;            // one wave per node

    // layer 1
    gemm_kernel<128><<<gemm_grid, 256, 0, stream>>>(x, W1, nullptr, dinv, bufA, n);
    gather_kernel<128><<<gath_grid, 256, 0, stream>>>(bufA, dinv, ptr, csr, bufB, n);
    // layer 2
    gemm_kernel<128><<<gemm_grid, 256, 0, stream>>>(bufB, W2, b1, dinv, bufA, n);
    gather_kernel<128><<<gath_grid, 256, 0, stream>>>(bufA, dinv, ptr, csr, bufB, n);
    // layer 3 (64-wide)
    gemm_kernel<64><<<gemm_grid, 256, 0, stream>>>(bufB, W3, b2, dinv, bufA, n);
    gather_kernel<64><<<gath_grid, 256, 0, stream>>>(bufA, dinv, ptr, csr, bufB, n);

    // fused relu(+b3) -> mean pool -> MLP
    pool_mlp_kernel<<<NGRAPH, 256, 0, stream>>>(bufB, b3, batch, Wf1, bf1, Wf2, bf2, out, n);
}

// Round 3
// 491.228 us; speedup vs baseline: 3.6659x; 1.1349x over previous
//
#include <hip/hip_runtime.h>

// GCN: 3x (GEMM -> normalized adjacency aggregate) + mean-pool + MLP.
// R2: atomic scatter -> CSR build + per-node gather (no float atomics).
// R3: single-block scan (77 us, 0.15% occupancy) -> 3-pass hierarchical scan.
//   out[c] = dinv[c] * ( hs[c] + sum_{(r->c)} hs[r] ),  hs = (X@W) * dinv[row]

#define NGRAPH 100

// ---------------- degree histogram (int) ----------------

__global__ void deg_kernel(const int* __restrict__ col, int* __restrict__ cnt, int E) {
    int e = blockIdx.x * blockDim.x + threadIdx.x;
    if (e < E) atomicAdd(&cnt[col[e]], 1);
}

__global__ void dinv_kernel(const int* __restrict__ cnt, float* __restrict__ dinv, int n) {
    int i = blockIdx.x * blockDim.x + threadIdx.x;
    if (i < n) dinv[i] = 1.0f / sqrtf((float)(cnt[i] + 1));   // +1 self-loop
}

// ---------------- hierarchical exclusive scan: cnt[0..n) -> ptr[0..n] ----------------
// pass 1: per-1024-chunk block sums

__global__ __launch_bounds__(256) void scan_part1(const int* __restrict__ cnt,
                                                  int* __restrict__ bsum, int n) {
    __shared__ int ts[256];
    const int b = blockIdx.x, t = threadIdx.x;
    const int base = b * 1024 + t * 4;
    int s = 0;
    if (base + 3 < n) { int4 q = *(const int4*)&cnt[base]; s = q.x + q.y + q.z + q.w; }
    else { for (int i = 0; i < 4; ++i) if (base + i < n) s += cnt[base + i]; }
    ts[t] = s;
    __syncthreads();
    for (int off = 128; off > 0; off >>= 1) {
        if (t < off) ts[t] += ts[t + off];
        __syncthreads();
    }
    if (t == 0) bsum[b] = ts[0];
}

// pass 2: exclusive scan of block sums (nblk <= 256), one block

__global__ __launch_bounds__(256) void scan_part2(int* __restrict__ bsum, int nblk) {
    __shared__ int ts[256];
    const int t = threadIdx.x;
    int v = (t < nblk) ? bsum[t] : 0;
    ts[t] = v;
    __syncthreads();
    for (int off = 1; off < 256; off <<= 1) {
        int x = (t >= off) ? ts[t - off] : 0;
        __syncthreads();
        ts[t] += x;
        __syncthreads();
    }
    if (t < nblk) bsum[t] = ts[t] - v;   // exclusive
}

// pass 3: re-scan each chunk + offset -> ptr

__global__ __launch_bounds__(256) void scan_part3(const int* __restrict__ cnt,
                                                  const int* __restrict__ bsum,
                                                  int* __restrict__ ptr, int n, int E) {
    __shared__ int ts[256];
    const int b = blockIdx.x, t = threadIdx.x;
    const int base = b * 1024 + t * 4;
    int v0 = 0, v1 = 0, v2 = 0, v3 = 0;
    if (base + 3 < n) {
        int4 q = *(const int4*)&cnt[base]; v0 = q.x; v1 = q.y; v2 = q.z; v3 = q.w;
    } else {
        if (base     < n) v0 = cnt[base];
        if (base + 1 < n) v1 = cnt[base + 1];
        if (base + 2 < n) v2 = cnt[base + 2];
        if (base + 3 < n) v3 = cnt[base + 3];
    }
    const int s = v0 + v1 + v2 + v3;
    ts[t] = s;
    __syncthreads();
    for (int off = 1; off < 256; off <<= 1) {
        int x = (t >= off) ? ts[t - off] : 0;
        __syncthreads();
        ts[t] += x;
        __syncthreads();
    }
    int excl = ts[t] - s + bsum[b];
    if (base     < n) ptr[base]     = excl;
    if (base + 1 < n) ptr[base + 1] = excl + v0;
    if (base + 2 < n) ptr[base + 2] = excl + v0 + v1;
    if (base + 3 < n) ptr[base + 3] = excl + v0 + v1 + v2;
    if (b == (int)gridDim.x - 1 && t == 255) ptr[n] = E;
}

// ---------------- CSR fill: csr[ptr[c] + cursor[c]++] = row[e] ----------------

__global__ void fill_kernel(const int* __restrict__ row, const int* __restrict__ col,
                            const int* __restrict__ ptr, int* __restrict__ cursor,
                            int* __restrict__ csr, int E) {
    int e = blockIdx.x * blockDim.x + threadIdx.x;
    if (e < E) {
        int c = col[e];
        int pos = atomicAdd(&cursor[c], 1);
        csr[ptr[c] + pos] = row[e];
    }
}

// ---------------- GEMM: Y[n,OUT] = transform(X[n,128]) @ W[128,OUT] * dinv[row] ----------
// transform(v,k) = bias_in ? relu(v + bias_in[k]) : v   (fuses prev layer's bias+relu)

template <int OUT>
__global__ void gemm_kernel(const float* __restrict__ X, const float* __restrict__ W,
                            const float* __restrict__ bias_in, const float* __restrict__ dinv,
                            float* __restrict__ Y, int n) {
    constexpr int CG  = OUT / 4;      // column groups of 4
    constexpr int RPB = 256 / CG;     // rows per block-iteration (8 or 16)
    __shared__ float Ws[128 * OUT];
    __shared__ float xs[RPB * 128];
    __shared__ float bs[128];

    const int t = threadIdx.x;
    for (int i = t * 4; i < 128 * OUT; i += 256 * 4)
        *(float4*)&Ws[i] = *(const float4*)&W[i];
    if (t < 128) bs[t] = (bias_in != nullptr) ? bias_in[t] : 0.0f;
    __syncthreads();

    const int cg = t % CG;
    const int rg = t / CG;
    const bool do_relu = (bias_in != nullptr);

    for (int row0 = blockIdx.x * RPB; row0 < n; row0 += gridDim.x * RPB) {
        for (int i = t; i < RPB * 32; i += 256) {
            int r  = i / 32;
            int cc = (i % 32) * 4;
            int gr = row0 + r;
            float4 v = make_float4(0.f, 0.f, 0.f, 0.f);
            if (gr < n) v = *(const float4*)&X[(size_t)gr * 128 + cc];
            if (do_relu) {
                v.x = fmaxf(v.x + bs[cc + 0], 0.f);
                v.y = fmaxf(v.y + bs[cc + 1], 0.f);
                v.z = fmaxf(v.z + bs[cc + 2], 0.f);
                v.w = fmaxf(v.w + bs[cc + 3], 0.f);
            }
            *(float4*)&xs[r * 128 + cc] = v;
        }
        __syncthreads();

        int gr = row0 + rg;
        if (gr < n) {
            float4 acc = make_float4(0.f, 0.f, 0.f, 0.f);
            #pragma unroll
            for (int k = 0; k < 128; k += 4) {
                float4 xv = *(const float4*)&xs[rg * 128 + k];
                float4 w0 = *(const float4*)&Ws[(k + 0) * OUT + cg * 4];
                float4 w1 = *(const float4*)&Ws[(k + 1) * OUT + cg * 4];
                float4 w2 = *(const float4*)&Ws[(k + 2) * OUT + cg * 4];
                float4 w3 = *(const float4*)&Ws[(k + 3) * OUT + cg * 4];
                acc.x += xv.x * w0.x; acc.y += xv.x * w0.y; acc.z += xv.x * w0.z; acc.w += xv.x * w0.w;
                acc.x += xv.y * w1.x; acc.y += xv.y * w1.y; acc.z += xv.y * w1.z; acc.w += xv.y * w1.w;
                acc.x += xv.z * w2.x; acc.y += xv.z * w2.y; acc.z += xv.z * w2.z; acc.w += xv.z * w2.w;
                acc.x += xv.w * w3.x; acc.y += xv.w * w3.y; acc.z += xv.w * w3.z; acc.w += xv.w * w3.w;
            }
            float dw = dinv[gr];
            acc.x *= dw; acc.y *= dw; acc.z *= dw; acc.w *= dw;
            *(float4*)&Y[(size_t)gr * OUT + cg * 4] = acc;
        }
        __syncthreads();
    }
}

// ---------------- gather: out[c,:] = dinv[c] * (hs[c,:] + sum_in hs[src,:]) ----------------
// one wave per destination node

template <int F>
__global__ void gather_kernel(const float* __restrict__ hs, const float* __restrict__ dinv,
                              const int* __restrict__ ptr, const int* __restrict__ csr,
                              float* __restrict__ out, int n) {
    const int lane = threadIdx.x & 63;
    const int c = (blockIdx.x * blockDim.x + threadIdx.x) >> 6;
    if (c >= n) return;
    const int beg = ptr[c], end = ptr[c + 1];
    const float w = dinv[c];

    if (F == 128) {
        const float2* h2 = (const float2*)hs;
        const size_t li = lane;
        float2 acc = h2[(size_t)c * 64 + li];            // self-loop
        int j = beg;
        for (; j + 4 <= end; j += 4) {
            int s0 = csr[j], s1 = csr[j + 1], s2 = csr[j + 2], s3 = csr[j + 3];
            float2 v0 = h2[(size_t)s0 * 64 + li];
            float2 v1 = h2[(size_t)s1 * 64 + li];
            float2 v2 = h2[(size_t)s2 * 64 + li];
            float2 v3 = h2[(size_t)s3 * 64 + li];
            acc.x += v0.x + v1.x + v2.x + v3.x;
            acc.y += v0.y + v1.y + v2.y + v3.y;
        }
        for (; j < end; ++j) {
            float2 v = h2[(size_t)csr[j] * 64 + li];
            acc.x += v.x; acc.y += v.y;
        }
        *(float2*)&out[(size_t)c * 128 + lane * 2] = make_float2(w * acc.x, w * acc.y);
    } else {     // F == 64
        float acc = hs[(size_t)c * 64 + lane];
        int j = beg;
        for (; j + 4 <= end; j += 4) {
            int s0 = csr[j], s1 = csr[j + 1], s2 = csr[j + 2], s3 = csr[j + 3];
            float v0 = hs[(size_t)s0 * 64 + lane];
            float v1 = hs[(size_t)s1 * 64 + lane];
            float v2 = hs[(size_t)s2 * 64 + lane];
            float v3 = hs[(size_t)s3 * 64 + lane];
            acc += v0 + v1 + v2 + v3;
        }
        for (; j < end; ++j) acc += hs[(size_t)csr[j] * 64 + lane];
        out[(size_t)c * 64 + lane] = w * acc;
    }
}

// ---------------- fused mean-pool + MLP head ----------------

__global__ void pool_mlp_kernel(const float* __restrict__ h, const float* __restrict__ b3,
                                const int* __restrict__ batch,
                                const float* __restrict__ Wf1, const float* __restrict__ bf1,
                                const float* __restrict__ Wf2, const float* __restrict__ bf2,
                                float* __restrict__ out, int n) {
    const int g = blockIdx.x;
    const int t = threadIdx.x;

    auto lb = [&](int v) {
        int lo = 0, hi = n;
        while (lo < hi) { int mid = (lo + hi) >> 1; if (batch[mid] < v) lo = mid + 1; else hi = mid; }
        return lo;
    };
    const int start = lb(g);
    const int end   = lb(g + 1);

    __shared__ float part[4][64];
    __shared__ float pooled[64];
    __shared__ float hid[32];

    const int f = t & 63, sub = t >> 6;
    const float bias = b3[f];
    float acc = 0.f;
    for (int i = start + sub; i < end; i += 4)
        acc += fmaxf(h[(size_t)i * 64 + f] + bias, 0.f);
    part[sub][f] = acc;
    __syncthreads();

    if (t < 64) {
        float s = part[0][t] + part[1][t] + part[2][t] + part[3][t];
        int cnt = end - start;
        pooled[t] = s / (float)(cnt > 0 ? cnt : 1);
    }
    __syncthreads();

    if (t < 32) {
        float a = bf1[t];
        #pragma unroll
        for (int k = 0; k < 64; ++k) a += pooled[k] * Wf1[k * 32 + t];
        hid[t] = fmaxf(a, 0.f);
    }
    __syncthreads();

    if (t < 10) {
        float a = bf2[t];
        #pragma unroll
        for (int k = 0; k < 32; ++k) a += hid[k] * Wf2[k * 10 + t];
        out[g * 10 + t] = a;
    }
}

// ---------------- launcher ----------------

extern "C" void kernel_launch(void* const* d_in, const int* in_sizes, int n_in,
                              void* d_out, int out_size, void* d_ws, size_t ws_size,
                              hipStream_t stream) {
    const float* x     = (const float*)d_in[0];
    const int*   edge  = (const int*)  d_in[1];
    const int*   batch = (const int*)  d_in[2];
    const float* W1    = (const float*)d_in[3];
    const float* b1    = (const float*)d_in[4];
    const float* W2    = (const float*)d_in[5];
    const float* b2    = (const float*)d_in[6];
    const float* W3    = (const float*)d_in[7];
    const float* b3    = (const float*)d_in[8];
    const float* Wf1   = (const float*)d_in[9];
    const float* bf1   = (const float*)d_in[10];
    const float* Wf2   = (const float*)d_in[11];
    const float* bf2   = (const float*)d_in[12];
    float* out = (float*)d_out;

    const int E = in_sizes[1] / 2;     // 800000
    const int n = in_sizes[2];         // 50000
    const int* row = edge;
    const int* col = edge + E;

    const int nblk = (n + 1023) / 1024;                    // scan chunks (49)

    const size_t n_pad = ((size_t)n + 64) & ~(size_t)63;   // >= n+1, 64-aligned
    char* wsb = (char*)d_ws;
    int*   cnt   = (int*)wsb;                    wsb += n_pad * 4;   // also reused as cursor
    int*   ptr   = (int*)wsb;                    wsb += n_pad * 4;
    float* dinv  = (float*)wsb;                  wsb += n_pad * 4;
    int*   bsum  = (int*)wsb;                    wsb += 256 * 4;
    int*   csr   = (int*)wsb;                    wsb += (((size_t)E + 63) & ~(size_t)63) * 4;
    float* bufA  = (float*)wsb;                  wsb += (size_t)n * 128 * 4;
    float* bufB  = (float*)wsb;

    // ---- CSR build (once, reused for all 3 layers) ----
    hipMemsetAsync(cnt, 0, (size_t)n * 4, stream);
    deg_kernel<<<(E + 255) / 256, 256, 0, stream>>>(col, cnt, E);
    dinv_kernel<<<(n + 255) / 256, 256, 0, stream>>>(cnt, dinv, n);
    scan_part1<<<nblk, 256, 0, stream>>>(cnt, bsum, n);
    scan_part2<<<1, 256, 0, stream>>>(bsum, nblk);
    scan_part3<<<nblk, 256, 0, stream>>>(cnt, bsum, ptr, n, E);
    hipMemsetAsync(cnt, 0, (size_t)n * 4, stream);         // cnt -> cursor
    fill_kernel<<<(E + 255) / 256, 256, 0, stream>>>(row, col, ptr, cnt, csr, E);

    const int gemm_grid = 1024;
    const int gath_grid = (n * 64 + 255) / 256;            // one wave per node

    // layer 1
    gemm_kernel<128><<<gemm_grid, 256, 0, stream>>>(x, W1, nullptr, dinv, bufA, n);
    gather_kernel<128><<<gath_grid, 256, 0, stream>>>(bufA, dinv, ptr, csr, bufB, n);
    // layer 2
    gemm_kernel<128><<<gemm_grid, 256, 0, stream>>>(bufB, W2, b1, dinv, bufA, n);
    gather_kernel<128><<<gath_grid, 256, 0, stream>>>(bufA, dinv, ptr, csr, bufB, n);
    // layer 3 (64-wide)
    gemm_kernel<64><<<gemm_grid, 256, 0, stream>>>(bufB, W3, b2, dinv, bufA, n);
    gather_kernel<64><<<gath_grid, 256, 0, stream>>>(bufA, dinv, ptr, csr, bufB, n);

    // fused relu(+b3) -> mean pool -> MLP
    pool_mlp_kernel<<<NGRAPH, 256, 0, stream>>>(bufB, b3, batch, Wf1, bf1, Wf2, bf2, out, n);
}

// Round 4
// 478.748 us; speedup vs baseline: 3.7615x; 1.0261x over previous
//
#include <hip/hip_runtime.h>

// GCN: 3x (GEMM -> normalized adjacency aggregate) + mean-pool + MLP.
// R2: atomic scatter -> CSR build + per-node gather (no float atomics).
// R3: hierarchical scan (77us single-block scan removed).
// R4: register-tiled GEMM (4x8 per thread, k-sliced LDS, 1.5 B/FMA vs 5 B/FMA);
//     dinv+cursor folded into scan_part3 (fill uses absolute cursor, -2 dispatches).
//   out[c] = dinv[c] * ( hs[c] + sum_{(r->c)} hs[r] ),  hs = (X@W) * dinv[row]

#define NGRAPH 100

// ---------------- degree histogram (int) ----------------

__global__ void deg_kernel(const int* __restrict__ col, int* __restrict__ cnt, int E) {
    int e = blockIdx.x * blockDim.x + threadIdx.x;
    if (e < E) atomicAdd(&cnt[col[e]], 1);
}

// ---------------- hierarchical exclusive scan: cnt[0..n) -> ptr[0..n] ----------------

__global__ __launch_bounds__(256) void scan_part1(const int* __restrict__ cnt,
                                                  int* __restrict__ bsum, int n) {
    __shared__ int ts[256];
    const int b = blockIdx.x, t = threadIdx.x;
    const int base = b * 1024 + t * 4;
    int s = 0;
    if (base + 3 < n) { int4 q = *(const int4*)&cnt[base]; s = q.x + q.y + q.z + q.w; }
    else { for (int i = 0; i < 4; ++i) if (base + i < n) s += cnt[base + i]; }
    ts[t] = s;
    __syncthreads();
    for (int off = 128; off > 0; off >>= 1) {
        if (t < off) ts[t] += ts[t + off];
        __syncthreads();
    }
    if (t == 0) bsum[b] = ts[0];
}

__global__ __launch_bounds__(256) void scan_part2(int* __restrict__ bsum, int nblk) {
    __shared__ int ts[256];
    const int t = threadIdx.x;
    int v = (t < nblk) ? bsum[t] : 0;
    ts[t] = v;
    __syncthreads();
    for (int off = 1; off < 256; off <<= 1) {
        int x = (t >= off) ? ts[t - off] : 0;
        __syncthreads();
        ts[t] += x;
        __syncthreads();
    }
    if (t < nblk) bsum[t] = ts[t] - v;   // exclusive
}

// pass 3: re-scan chunk + offset -> ptr; also cursor init (= ptr) and dinv.
// cursor may alias cnt (each thread reads its own cnt elements before writing).

__global__ __launch_bounds__(256) void scan_part3(const int* __restrict__ cnt,
                                                  const int* __restrict__ bsum,
                                                  int* __restrict__ ptr,
                                                  int* __restrict__ cursor,
                                                  float* __restrict__ dinv,
                                                  int n, int E) {
    __shared__ int ts[256];
    const int b = blockIdx.x, t = threadIdx.x;
    const int base = b * 1024 + t * 4;
    int v0 = 0, v1 = 0, v2 = 0, v3 = 0;
    if (base + 3 < n) {
        int4 q = *(const int4*)&cnt[base]; v0 = q.x; v1 = q.y; v2 = q.z; v3 = q.w;
    } else {
        if (base     < n) v0 = cnt[base];
        if (base + 1 < n) v1 = cnt[base + 1];
        if (base + 2 < n) v2 = cnt[base + 2];
        if (base + 3 < n) v3 = cnt[base + 3];
    }
    const int s = v0 + v1 + v2 + v3;
    ts[t] = s;
    __syncthreads();
    for (int off = 1; off < 256; off <<= 1) {
        int x = (t >= off) ? ts[t - off] : 0;
        __syncthreads();
        ts[t] += x;
        __syncthreads();
    }
    int e0 = ts[t] - s + bsum[b];
    int e1 = e0 + v0, e2 = e1 + v1, e3 = e2 + v2;
    if (base < n) {
        ptr[base] = e0; cursor[base] = e0;
        dinv[base] = 1.0f / sqrtf((float)(v0 + 1));
    }
    if (base + 1 < n) {
        ptr[base + 1] = e1; cursor[base + 1] = e1;
        dinv[base + 1] = 1.0f / sqrtf((float)(v1 + 1));
    }
    if (base + 2 < n) {
        ptr[base + 2] = e2; cursor[base + 2] = e2;
        dinv[base + 2] = 1.0f / sqrtf((float)(v2 + 1));
    }
    if (base + 3 < n) {
        ptr[base + 3] = e3; cursor[base + 3] = e3;
        dinv[base + 3] = 1.0f / sqrtf((float)(v3 + 1));
    }
    if (b == (int)gridDim.x - 1 && t == 255) ptr[n] = E;
}

// ---------------- CSR fill: csr[cursor[c]++] = row[e] (cursor pre-seeded with ptr) ----

__global__ void fill_kernel(const int* __restrict__ row, const int* __restrict__ col,
                            int* __restrict__ cursor, int* __restrict__ csr, int E) {
    int e = blockIdx.x * blockDim.x + threadIdx.x;
    if (e < E) {
        int pos = atomicAdd(&cursor[col[e]], 1);
        csr[pos] = row[e];
    }
}

// ---------------- GEMM: Y[n,OUT] = transform(X[n,128]) @ W[128,OUT] * dinv[row] ----------
// Register-tiled: thread computes 4 rows x 8 cols; W k-sliced (32) in LDS.
// transform(v,k) = bias_in ? relu(v + bias_in[k]) : v   (fuses prev layer's bias+relu)

template <int OUT>
__global__ __launch_bounds__(256) void gemm_kernel(const float* __restrict__ X,
                                                   const float* __restrict__ W,
                                                   const float* __restrict__ bias_in,
                                                   const float* __restrict__ dinv,
                                                   float* __restrict__ Y, int n) {
    constexpr int CG = OUT / 8;       // col groups of 8 (16 or 8)
    constexpr int RG = 256 / CG;      // row groups (16 or 32)
    constexpr int R  = RG * 4;        // rows per block (64 or 128)
    __shared__ float Ws[32 * OUT];    // W k-slice
    __shared__ float Xs[R * 32];      // X row-tile k-slice
    __shared__ float bs[128];

    const int t = threadIdx.x;
    if (t < 128) bs[t] = (bias_in != nullptr) ? bias_in[t] : 0.0f;
    __syncthreads();

    const int cg = t % CG;            // cols cg*8 .. cg*8+7 (lanes vary fastest -> bcast X)
    const int rg = t / CG;            // rows rg*4 .. rg*4+3 (block-relative)
    const int row0 = blockIdx.x * R;
    const bool do_relu = (bias_in != nullptr);

    float acc[4][8];
    #pragma unroll
    for (int i = 0; i < 4; ++i)
        #pragma unroll
        for (int j = 0; j < 8; ++j) acc[i][j] = 0.0f;

    for (int ks = 0; ks < 128; ks += 32) {
        // stage W slice: rows ks..ks+31, contiguous
        for (int i = t * 4; i < 32 * OUT; i += 1024)
            *(float4*)&Ws[i] = *(const float4*)&W[ks * OUT + i];
        // stage X tile: R rows x 32 k (with fused bias+relu)
        for (int i = t; i < R * 8; i += 256) {
            int r = i / 8, f4 = (i % 8) * 4;
            int gr = row0 + r;
            float4 v = make_float4(0.f, 0.f, 0.f, 0.f);
            if (gr < n) v = *(const float4*)&X[(size_t)gr * 128 + ks + f4];
            if (do_relu) {
                int k = ks + f4;
                v.x = fmaxf(v.x + bs[k + 0], 0.f);
                v.y = fmaxf(v.y + bs[k + 1], 0.f);
                v.z = fmaxf(v.z + bs[k + 2], 0.f);
                v.w = fmaxf(v.w + bs[k + 3], 0.f);
            }
            *(float4*)&Xs[r * 32 + f4] = v;
        }
        __syncthreads();

        #pragma unroll
        for (int kk = 0; kk < 32; kk += 4) {
            float xr[4][4];
            #pragma unroll
            for (int i = 0; i < 4; ++i) {
                float4 tv = *(const float4*)&Xs[(rg * 4 + i) * 32 + kk];
                xr[i][0] = tv.x; xr[i][1] = tv.y; xr[i][2] = tv.z; xr[i][3] = tv.w;
            }
            #pragma unroll
            for (int j = 0; j < 4; ++j) {
                float4 wa = *(const float4*)&Ws[(kk + j) * OUT + cg * 8];
                float4 wb = *(const float4*)&Ws[(kk + j) * OUT + cg * 8 + 4];
                #pragma unroll
                for (int i = 0; i < 4; ++i) {
                    float xv = xr[i][j];
                    acc[i][0] += xv * wa.x; acc[i][1] += xv * wa.y;
                    acc[i][2] += xv * wa.z; acc[i][3] += xv * wa.w;
                    acc[i][4] += xv * wb.x; acc[i][5] += xv * wb.y;
                    acc[i][6] += xv * wb.z; acc[i][7] += xv * wb.w;
                }
            }
        }
        __syncthreads();
    }

    // epilogue: scale by dinv[row], store
    #pragma unroll
    for (int i = 0; i < 4; ++i) {
        int gr = row0 + rg * 4 + i;
        if (gr < n) {
            float dw = dinv[gr];
            float4 o0 = make_float4(acc[i][0] * dw, acc[i][1] * dw, acc[i][2] * dw, acc[i][3] * dw);
            float4 o1 = make_float4(acc[i][4] * dw, acc[i][5] * dw, acc[i][6] * dw, acc[i][7] * dw);
            *(float4*)&Y[(size_t)gr * OUT + cg * 8]     = o0;
            *(float4*)&Y[(size_t)gr * OUT + cg * 8 + 4] = o1;
        }
    }
}

// ---------------- gather: out[c,:] = dinv[c] * (hs[c,:] + sum_in hs[src,:]) ----------------
// one wave per destination node

template <int F>
__global__ void gather_kernel(const float* __restrict__ hs, const float* __restrict__ dinv,
                              const int* __restrict__ ptr, const int* __restrict__ csr,
                              float* __restrict__ out, int n) {
    const int lane = threadIdx.x & 63;
    const int c = (blockIdx.x * blockDim.x + threadIdx.x) >> 6;
    if (c >= n) return;
    const int beg = ptr[c], end = ptr[c + 1];
    const float w = dinv[c];

    if (F == 128) {
        const float2* h2 = (const float2*)hs;
        const size_t li = lane;
        float2 acc = h2[(size_t)c * 64 + li];            // self-loop
        int j = beg;
        for (; j + 4 <= end; j += 4) {
            int s0 = csr[j], s1 = csr[j + 1], s2 = csr[j + 2], s3 = csr[j + 3];
            float2 v0 = h2[(size_t)s0 * 64 + li];
            float2 v1 = h2[(size_t)s1 * 64 + li];
            float2 v2 = h2[(size_t)s2 * 64 + li];
            float2 v3 = h2[(size_t)s3 * 64 + li];
            acc.x += v0.x + v1.x + v2.x + v3.x;
            acc.y += v0.y + v1.y + v2.y + v3.y;
        }
        for (; j < end; ++j) {
            float2 v = h2[(size_t)csr[j] * 64 + li];
            acc.x += v.x; acc.y += v.y;
        }
        *(float2*)&out[(size_t)c * 128 + lane * 2] = make_float2(w * acc.x, w * acc.y);
    } else {     // F == 64
        float acc = hs[(size_t)c * 64 + lane];
        int j = beg;
        for (; j + 4 <= end; j += 4) {
            int s0 = csr[j], s1 = csr[j + 1], s2 = csr[j + 2], s3 = csr[j + 3];
            float v0 = hs[(size_t)s0 * 64 + lane];
            float v1 = hs[(size_t)s1 * 64 + lane];
            float v2 = hs[(size_t)s2 * 64 + lane];
            float v3 = hs[(size_t)s3 * 64 + lane];
            acc += v0 + v1 + v2 + v3;
        }
        for (; j < end; ++j) acc += hs[(size_t)csr[j] * 64 + lane];
        out[(size_t)c * 64 + lane] = w * acc;
    }
}

// ---------------- fused mean-pool + MLP head ----------------

__global__ void pool_mlp_kernel(const float* __restrict__ h, const float* __restrict__ b3,
                                const int* __restrict__ batch,
                                const float* __restrict__ Wf1, const float* __restrict__ bf1,
                                const float* __restrict__ Wf2, const float* __restrict__ bf2,
                                float* __restrict__ out, int n) {
    const int g = blockIdx.x;
    const int t = threadIdx.x;

    auto lb = [&](int v) {
        int lo = 0, hi = n;
        while (lo < hi) { int mid = (lo + hi) >> 1; if (batch[mid] < v) lo = mid + 1; else hi = mid; }
        return lo;
    };
    const int start = lb(g);
    const int end   = lb(g + 1);

    __shared__ float part[4][64];
    __shared__ float pooled[64];
    __shared__ float hid[32];

    const int f = t & 63, sub = t >> 6;
    const float bias = b3[f];
    float acc = 0.f;
    for (int i = start + sub; i < end; i += 4)
        acc += fmaxf(h[(size_t)i * 64 + f] + bias, 0.f);
    part[sub][f] = acc;
    __syncthreads();

    if (t < 64) {
        float s = part[0][t] + part[1][t] + part[2][t] + part[3][t];
        int cnt = end - start;
        pooled[t] = s / (float)(cnt > 0 ? cnt : 1);
    }
    __syncthreads();

    if (t < 32) {
        float a = bf1[t];
        #pragma unroll
        for (int k = 0; k < 64; ++k) a += pooled[k] * Wf1[k * 32 + t];
        hid[t] = fmaxf(a, 0.f);
    }
    __syncthreads();

    if (t < 10) {
        float a = bf2[t];
        #pragma unroll
        for (int k = 0; k < 32; ++k) a += hid[k] * Wf2[k * 10 + t];
        out[g * 10 + t] = a;
    }
}

// ---------------- launcher ----------------

extern "C" void kernel_launch(void* const* d_in, const int* in_sizes, int n_in,
                              void* d_out, int out_size, void* d_ws, size_t ws_size,
                              hipStream_t stream) {
    const float* x     = (const float*)d_in[0];
    const int*   edge  = (const int*)  d_in[1];
    const int*   batch = (const int*)  d_in[2];
    const float* W1    = (const float*)d_in[3];
    const float* b1    = (const float*)d_in[4];
    const float* W2    = (const float*)d_in[5];
    const float* b2    = (const float*)d_in[6];
    const float* W3    = (const float*)d_in[7];
    const float* b3    = (const float*)d_in[8];
    const float* Wf1   = (const float*)d_in[9];
    const float* bf1   = (const float*)d_in[10];
    const float* Wf2   = (const float*)d_in[11];
    const float* bf2   = (const float*)d_in[12];
    float* out = (float*)d_out;

    const int E = in_sizes[1] / 2;     // 800000
    const int n = in_sizes[2];         // 50000
    const int* row = edge;
    const int* col = edge + E;

    const int nblk = (n + 1023) / 1024;                    // scan chunks (49)

    const size_t n_pad = ((size_t)n + 64) & ~(size_t)63;   // >= n+1, 64-aligned
    char* wsb = (char*)d_ws;
    int*   cnt   = (int*)wsb;                    wsb += n_pad * 4;   // reused as cursor
    int*   ptr   = (int*)wsb;                    wsb += n_pad * 4;
    float* dinv  = (float*)wsb;                  wsb += n_pad * 4;
    int*   bsum  = (int*)wsb;                    wsb += 256 * 4;
    int*   csr   = (int*)wsb;                    wsb += (((size_t)E + 63) & ~(size_t)63) * 4;
    float* bufA  = (float*)wsb;                  wsb += (size_t)n * 128 * 4;
    float* bufB  = (float*)wsb;

    // ---- CSR build (once, reused for all 3 layers) ----
    hipMemsetAsync(cnt, 0, (size_t)n * 4, stream);
    deg_kernel<<<(E + 255) / 256, 256, 0, stream>>>(col, cnt, E);
    scan_part1<<<nblk, 256, 0, stream>>>(cnt, bsum, n);
    scan_part2<<<1, 256, 0, stream>>>(bsum, nblk);
    scan_part3<<<nblk, 256, 0, stream>>>(cnt, bsum, ptr, cnt, dinv, n, E);  // cursor aliases cnt
    fill_kernel<<<(E + 255) / 256, 256, 0, stream>>>(row, col, cnt, csr, E);

    const int g128 = (n + 63) / 64;    // gemm<128> blocks (64 rows each)
    const int g64  = (n + 127) / 128;  // gemm<64>  blocks (128 rows each)
    const int gath_grid = (n * 64 + 255) / 256;            // one wave per node

    // layer 1
    gemm_kernel<128><<<g128, 256, 0, stream>>>(x, W1, nullptr, dinv, bufA, n);
    gather_kernel<128><<<gath_grid, 256, 0, stream>>>(bufA, dinv, ptr, csr, bufB, n);
    // layer 2
    gemm_kernel<128><<<g128, 256, 0, stream>>>(bufB, W2, b1, dinv, bufA, n);
    gather_kernel<128><<<gath_grid, 256, 0, stream>>>(bufA, dinv, ptr, csr, bufB, n);
    // layer 3 (64-wide)
    gemm_kernel<64><<<g64, 256, 0, stream>>>(bufB, W3, b2, dinv, bufA, n);
    gather_kernel<64><<<gath_grid, 256, 0, stream>>>(bufA, dinv, ptr, csr, bufB, n);

    // fused relu(+b3) -> mean pool -> MLP
    pool_mlp_kernel<<<NGRAPH, 256, 0, stream>>>(bufB, b3, batch, Wf1, bf1, Wf2, bf2, out, n);
}

// Round 5
// 469.989 us; speedup vs baseline: 3.8316x; 1.0186x over previous
//
#include <hip/hip_runtime.h>

// GCN: 3x (GEMM -> normalized adjacency aggregate) + mean-pool + MLP.
// R2: atomic scatter -> CSR build + per-node gather (no float atomics).
// R3: hierarchical scan.
// R4: register-tiled GEMM; CSR-build dispatch fusion.
// R5: gather rebuilt for memory-level parallelism: half-wave (F=128) /
//     quarter-wave (F=64) edge streams, float4 row loads, 4-deep unroll
//     -> 8-16 outstanding 16B loads per wave (was 4x8B). shfl-combine.
//   out[c] = dinv[c] * ( hs[c] + sum_{(r->c)} hs[r] ),  hs = (X@W) * dinv[row]

#define NGRAPH 100

// ---------------- degree histogram (int) ----------------

__global__ void deg_kernel(const int* __restrict__ col, int* __restrict__ cnt, int E) {
    int e = blockIdx.x * blockDim.x + threadIdx.x;
    if (e < E) atomicAdd(&cnt[col[e]], 1);
}

// ---------------- hierarchical exclusive scan: cnt[0..n) -> ptr[0..n] ----------------

__global__ __launch_bounds__(256) void scan_part1(const int* __restrict__ cnt,
                                                  int* __restrict__ bsum, int n) {
    __shared__ int ts[256];
    const int b = blockIdx.x, t = threadIdx.x;
    const int base = b * 1024 + t * 4;
    int s = 0;
    if (base + 3 < n) { int4 q = *(const int4*)&cnt[base]; s = q.x + q.y + q.z + q.w; }
    else { for (int i = 0; i < 4; ++i) if (base + i < n) s += cnt[base + i]; }
    ts[t] = s;
    __syncthreads();
    for (int off = 128; off > 0; off >>= 1) {
        if (t < off) ts[t] += ts[t + off];
        __syncthreads();
    }
    if (t == 0) bsum[b] = ts[0];
}

__global__ __launch_bounds__(256) void scan_part2(int* __restrict__ bsum, int nblk) {
    __shared__ int ts[256];
    const int t = threadIdx.x;
    int v = (t < nblk) ? bsum[t] : 0;
    ts[t] = v;
    __syncthreads();
    for (int off = 1; off < 256; off <<= 1) {
        int x = (t >= off) ? ts[t - off] : 0;
        __syncthreads();
        ts[t] += x;
        __syncthreads();
    }
    if (t < nblk) bsum[t] = ts[t] - v;   // exclusive
}

// pass 3: re-scan chunk + offset -> ptr; also cursor init (= ptr) and dinv.
// cursor may alias cnt (each thread reads its own cnt elements before writing).

__global__ __launch_bounds__(256) void scan_part3(const int* __restrict__ cnt,
                                                  const int* __restrict__ bsum,
                                                  int* __restrict__ ptr,
                                                  int* __restrict__ cursor,
                                                  float* __restrict__ dinv,
                                                  int n, int E) {
    __shared__ int ts[256];
    const int b = blockIdx.x, t = threadIdx.x;
    const int base = b * 1024 + t * 4;
    int v0 = 0, v1 = 0, v2 = 0, v3 = 0;
    if (base + 3 < n) {
        int4 q = *(const int4*)&cnt[base]; v0 = q.x; v1 = q.y; v2 = q.z; v3 = q.w;
    } else {
        if (base     < n) v0 = cnt[base];
        if (base + 1 < n) v1 = cnt[base + 1];
        if (base + 2 < n) v2 = cnt[base + 2];
        if (base + 3 < n) v3 = cnt[base + 3];
    }
    const int s = v0 + v1 + v2 + v3;
    ts[t] = s;
    __syncthreads();
    for (int off = 1; off < 256; off <<= 1) {
        int x = (t >= off) ? ts[t - off] : 0;
        __syncthreads();
        ts[t] += x;
        __syncthreads();
    }
    int e0 = ts[t] - s + bsum[b];
    int e1 = e0 + v0, e2 = e1 + v1, e3 = e2 + v2;
    if (base < n) {
        ptr[base] = e0; cursor[base] = e0;
        dinv[base] = 1.0f / sqrtf((float)(v0 + 1));
    }
    if (base + 1 < n) {
        ptr[base + 1] = e1; cursor[base + 1] = e1;
        dinv[base + 1] = 1.0f / sqrtf((float)(v1 + 1));
    }
    if (base + 2 < n) {
        ptr[base + 2] = e2; cursor[base + 2] = e2;
        dinv[base + 2] = 1.0f / sqrtf((float)(v2 + 1));
    }
    if (base + 3 < n) {
        ptr[base + 3] = e3; cursor[base + 3] = e3;
        dinv[base + 3] = 1.0f / sqrtf((float)(v3 + 1));
    }
    if (b == (int)gridDim.x - 1 && t == 255) ptr[n] = E;
}

// ---------------- CSR fill: csr[cursor[c]++] = row[e] (cursor pre-seeded with ptr) ----

__global__ void fill_kernel(const int* __restrict__ row, const int* __restrict__ col,
                            int* __restrict__ cursor, int* __restrict__ csr, int E) {
    int e = blockIdx.x * blockDim.x + threadIdx.x;
    if (e < E) {
        int pos = atomicAdd(&cursor[col[e]], 1);
        csr[pos] = row[e];
    }
}

// ---------------- GEMM: Y[n,OUT] = transform(X[n,128]) @ W[128,OUT] * dinv[row] ----------
// Register-tiled: thread computes 4 rows x 8 cols; W k-sliced (32) in LDS.
// transform(v,k) = bias_in ? relu(v + bias_in[k]) : v   (fuses prev layer's bias+relu)

template <int OUT>
__global__ __launch_bounds__(256) void gemm_kernel(const float* __restrict__ X,
                                                   const float* __restrict__ W,
                                                   const float* __restrict__ bias_in,
                                                   const float* __restrict__ dinv,
                                                   float* __restrict__ Y, int n) {
    constexpr int CG = OUT / 8;       // col groups of 8 (16 or 8)
    constexpr int RG = 256 / CG;      // row groups (16 or 32)
    constexpr int R  = RG * 4;        // rows per block (64 or 128)
    __shared__ float Ws[32 * OUT];    // W k-slice
    __shared__ float Xs[R * 32];      // X row-tile k-slice
    __shared__ float bs[128];

    const int t = threadIdx.x;
    if (t < 128) bs[t] = (bias_in != nullptr) ? bias_in[t] : 0.0f;
    __syncthreads();

    const int cg = t % CG;            // cols cg*8 .. cg*8+7 (lanes vary fastest -> bcast X)
    const int rg = t / CG;            // rows rg*4 .. rg*4+3 (block-relative)
    const int row0 = blockIdx.x * R;
    const bool do_relu = (bias_in != nullptr);

    float acc[4][8];
    #pragma unroll
    for (int i = 0; i < 4; ++i)
        #pragma unroll
        for (int j = 0; j < 8; ++j) acc[i][j] = 0.0f;

    for (int ks = 0; ks < 128; ks += 32) {
        for (int i = t * 4; i < 32 * OUT; i += 1024)
            *(float4*)&Ws[i] = *(const float4*)&W[ks * OUT + i];
        for (int i = t; i < R * 8; i += 256) {
            int r = i / 8, f4 = (i % 8) * 4;
            int gr = row0 + r;
            float4 v = make_float4(0.f, 0.f, 0.f, 0.f);
            if (gr < n) v = *(const float4*)&X[(size_t)gr * 128 + ks + f4];
            if (do_relu) {
                int k = ks + f4;
                v.x = fmaxf(v.x + bs[k + 0], 0.f);
                v.y = fmaxf(v.y + bs[k + 1], 0.f);
                v.z = fmaxf(v.z + bs[k + 2], 0.f);
                v.w = fmaxf(v.w + bs[k + 3], 0.f);
            }
            *(float4*)&Xs[r * 32 + f4] = v;
        }
        __syncthreads();

        #pragma unroll
        for (int kk = 0; kk < 32; kk += 4) {
            float xr[4][4];
            #pragma unroll
            for (int i = 0; i < 4; ++i) {
                float4 tv = *(const float4*)&Xs[(rg * 4 + i) * 32 + kk];
                xr[i][0] = tv.x; xr[i][1] = tv.y; xr[i][2] = tv.z; xr[i][3] = tv.w;
            }
            #pragma unroll
            for (int j = 0; j < 4; ++j) {
                float4 wa = *(const float4*)&Ws[(kk + j) * OUT + cg * 8];
                float4 wb = *(const float4*)&Ws[(kk + j) * OUT + cg * 8 + 4];
                #pragma unroll
                for (int i = 0; i < 4; ++i) {
                    float xv = xr[i][j];
                    acc[i][0] += xv * wa.x; acc[i][1] += xv * wa.y;
                    acc[i][2] += xv * wa.z; acc[i][3] += xv * wa.w;
                    acc[i][4] += xv * wb.x; acc[i][5] += xv * wb.y;
                    acc[i][6] += xv * wb.z; acc[i][7] += xv * wb.w;
                }
            }
        }
        __syncthreads();
    }

    #pragma unroll
    for (int i = 0; i < 4; ++i) {
        int gr = row0 + rg * 4 + i;
        if (gr < n) {
            float dw = dinv[gr];
            float4 o0 = make_float4(acc[i][0] * dw, acc[i][1] * dw, acc[i][2] * dw, acc[i][3] * dw);
            float4 o1 = make_float4(acc[i][4] * dw, acc[i][5] * dw, acc[i][6] * dw, acc[i][7] * dw);
            *(float4*)&Y[(size_t)gr * OUT + cg * 8]     = o0;
            *(float4*)&Y[(size_t)gr * OUT + cg * 8 + 4] = o1;
        }
    }
}

// ---------------- gather: out[c,:] = dinv[c] * (hs[c,:] + sum_in hs[src,:]) ----------------
// R5: one wave per node, split into sub-waves each loading a FULL row as float4
// (F=128: 2 halves x 32 lanes; F=64: 4 quarters x 16 lanes). Sub-waves process
// interleaved edge streams -> up to 16 outstanding dwordx4 loads per wave.
// Streams combined at the end with __shfl xor.

template <int F>
__global__ void gather_kernel(const float* __restrict__ hs, const float* __restrict__ dinv,
                              const int* __restrict__ ptr, const int* __restrict__ csr,
                              float* __restrict__ out, int n) {
    const int lane = threadIdx.x & 63;
    const int c = (blockIdx.x * blockDim.x + threadIdx.x) >> 6;
    if (c >= n) return;
    const int beg = ptr[c], end = ptr[c + 1];
    const float w = dinv[c];
    const float4* h4 = (const float4*)hs;

    if (F == 128) {
        const int half = lane >> 5;          // 0 or 1: edge stream id
        const int l    = lane & 31;          // float4 index within row (32 x 16B = 512B)
        float4 acc = make_float4(0.f, 0.f, 0.f, 0.f);
        if (half == 0) acc = h4[(size_t)c * 32 + l];          // self-loop (once)
        int j = beg + half;
        for (; j + 6 < end; j += 8) {        // 4-deep unroll per stream
            int s0 = csr[j], s1 = csr[j + 2], s2 = csr[j + 4], s3 = csr[j + 6];
            float4 v0 = h4[(size_t)s0 * 32 + l];
            float4 v1 = h4[(size_t)s1 * 32 + l];
            float4 v2 = h4[(size_t)s2 * 32 + l];
            float4 v3 = h4[(size_t)s3 * 32 + l];
            acc.x += v0.x + v1.x + v2.x + v3.x;
            acc.y += v0.y + v1.y + v2.y + v3.y;
            acc.z += v0.z + v1.z + v2.z + v3.z;
            acc.w += v0.w + v1.w + v2.w + v3.w;
        }
        for (; j < end; j += 2) {
            float4 v = h4[(size_t)csr[j] * 32 + l];
            acc.x += v.x; acc.y += v.y; acc.z += v.z; acc.w += v.w;
        }
        // combine the two streams (lane <-> lane^32 hold same features)
        acc.x += __shfl(acc.x, lane ^ 32);
        acc.y += __shfl(acc.y, lane ^ 32);
        acc.z += __shfl(acc.z, lane ^ 32);
        acc.w += __shfl(acc.w, lane ^ 32);
        if (half == 0) {
            float4 o = make_float4(w * acc.x, w * acc.y, w * acc.z, w * acc.w);
            ((float4*)out)[(size_t)c * 32 + l] = o;
        }
    } else {     // F == 64: 4 quarter-wave streams, 16 x 16B = 256B rows
        const int q = lane >> 4;             // stream id 0..3
        const int l = lane & 15;             // float4 index within row
        float4 acc = make_float4(0.f, 0.f, 0.f, 0.f);
        if (q == 0) acc = h4[(size_t)c * 16 + l];             // self-loop (once)
        int j = beg + q;
        for (; j + 12 < end; j += 16) {      // 4-deep unroll per stream
            int s0 = csr[j], s1 = csr[j + 4], s2 = csr[j + 8], s3 = csr[j + 12];
            float4 v0 = h4[(size_t)s0 * 16 + l];
            float4 v1 = h4[(size_t)s1 * 16 + l];
            float4 v2 = h4[(size_t)s2 * 16 + l];
            float4 v3 = h4[(size_t)s3 * 16 + l];
            acc.x += v0.x + v1.x + v2.x + v3.x;
            acc.y += v0.y + v1.y + v2.y + v3.y;
            acc.z += v0.z + v1.z + v2.z + v3.z;
            acc.w += v0.w + v1.w + v2.w + v3.w;
        }
        for (; j < end; j += 4) {
            float4 v = h4[(size_t)csr[j] * 16 + l];
            acc.x += v.x; acc.y += v.y; acc.z += v.z; acc.w += v.w;
        }
        // combine 4 streams: xor 16 then xor 32
        acc.x += __shfl(acc.x, lane ^ 16);
        acc.y += __shfl(acc.y, lane ^ 16);
        acc.z += __shfl(acc.z, lane ^ 16);
        acc.w += __shfl(acc.w, lane ^ 16);
        acc.x += __shfl(acc.x, lane ^ 32);
        acc.y += __shfl(acc.y, lane ^ 32);
        acc.z += __shfl(acc.z, lane ^ 32);
        acc.w += __shfl(acc.w, lane ^ 32);
        if (q == 0) {
            float4 o = make_float4(w * acc.x, w * acc.y, w * acc.z, w * acc.w);
            ((float4*)out)[(size_t)c * 16 + l] = o;
        }
    }
}

// ---------------- fused mean-pool + MLP head ----------------

__global__ void pool_mlp_kernel(const float* __restrict__ h, const float* __restrict__ b3,
                                const int* __restrict__ batch,
                                const float* __restrict__ Wf1, const float* __restrict__ bf1,
                                const float* __restrict__ Wf2, const float* __restrict__ bf2,
                                float* __restrict__ out, int n) {
    const int g = blockIdx.x;
    const int t = threadIdx.x;

    auto lb = [&](int v) {
        int lo = 0, hi = n;
        while (lo < hi) { int mid = (lo + hi) >> 1; if (batch[mid] < v) lo = mid + 1; else hi = mid; }
        return lo;
    };
    const int start = lb(g);
    const int end   = lb(g + 1);

    __shared__ float part[4][64];
    __shared__ float pooled[64];
    __shared__ float hid[32];

    const int f = t & 63, sub = t >> 6;
    const float bias = b3[f];
    float acc = 0.f;
    for (int i = start + sub; i < end; i += 4)
        acc += fmaxf(h[(size_t)i * 64 + f] + bias, 0.f);
    part[sub][f] = acc;
    __syncthreads();

    if (t < 64) {
        float s = part[0][t] + part[1][t] + part[2][t] + part[3][t];
        int cnt = end - start;
        pooled[t] = s / (float)(cnt > 0 ? cnt : 1);
    }
    __syncthreads();

    if (t < 32) {
        float a = bf1[t];
        #pragma unroll
        for (int k = 0; k < 64; ++k) a += pooled[k] * Wf1[k * 32 + t];
        hid[t] = fmaxf(a, 0.f);
    }
    __syncthreads();

    if (t < 10) {
        float a = bf2[t];
        #pragma unroll
        for (int k = 0; k < 32; ++k) a += hid[k] * Wf2[k * 10 + t];
        out[g * 10 + t] = a;
    }
}

// ---------------- launcher ----------------

extern "C" void kernel_launch(void* const* d_in, const int* in_sizes, int n_in,
                              void* d_out, int out_size, void* d_ws, size_t ws_size,
                              hipStream_t stream) {
    const float* x     = (const float*)d_in[0];
    const int*   edge  = (const int*)  d_in[1];
    const int*   batch = (const int*)  d_in[2];
    const float* W1    = (const float*)d_in[3];
    const float* b1    = (const float*)d_in[4];
    const float* W2    = (const float*)d_in[5];
    const float* b2    = (const float*)d_in[6];
    const float* W3    = (const float*)d_in[7];
    const float* b3    = (const float*)d_in[8];
    const float* Wf1   = (const float*)d_in[9];
    const float* bf1   = (const float*)d_in[10];
    const float* Wf2   = (const float*)d_in[11];
    const float* bf2   = (const float*)d_in[12];
    float* out = (float*)d_out;

    const int E = in_sizes[1] / 2;     // 800000
    const int n = in_sizes[2];         // 50000
    const int* row = edge;
    const int* col = edge + E;

    const int nblk = (n + 1023) / 1024;                    // scan chunks (49)

    const size_t n_pad = ((size_t)n + 64) & ~(size_t)63;   // >= n+1, 64-aligned
    char* wsb = (char*)d_ws;
    int*   cnt   = (int*)wsb;                    wsb += n_pad * 4;   // reused as cursor
    int*   ptr   = (int*)wsb;                    wsb += n_pad * 4;
    float* dinv  = (float*)wsb;                  wsb += n_pad * 4;
    int*   bsum  = (int*)wsb;                    wsb += 256 * 4;
    int*   csr   = (int*)wsb;                    wsb += (((size_t)E + 63) & ~(size_t)63) * 4;
    float* bufA  = (float*)wsb;                  wsb += (size_t)n * 128 * 4;
    float* bufB  = (float*)wsb;

    // ---- CSR build (once, reused for all 3 layers) ----
    hipMemsetAsync(cnt, 0, (size_t)n * 4, stream);
    deg_kernel<<<(E + 255) / 256, 256, 0, stream>>>(col, cnt, E);
    scan_part1<<<nblk, 256, 0, stream>>>(cnt, bsum, n);
    scan_part2<<<1, 256, 0, stream>>>(bsum, nblk);
    scan_part3<<<nblk, 256, 0, stream>>>(cnt, bsum, ptr, cnt, dinv, n, E);  // cursor aliases cnt
    fill_kernel<<<(E + 255) / 256, 256, 0, stream>>>(row, col, cnt, csr, E);

    const int g128 = (n + 63) / 64;    // gemm<128> blocks (64 rows each)
    const int g64  = (n + 127) / 128;  // gemm<64>  blocks (128 rows each)
    const int gath_grid = (n * 64 + 255) / 256;            // one wave per node

    // layer 1
    gemm_kernel<128><<<g128, 256, 0, stream>>>(x, W1, nullptr, dinv, bufA, n);
    gather_kernel<128><<<gath_grid, 256, 0, stream>>>(bufA, dinv, ptr, csr, bufB, n);
    // layer 2
    gemm_kernel<128><<<g128, 256, 0, stream>>>(bufB, W2, b1, dinv, bufA, n);
    gather_kernel<128><<<gath_grid, 256, 0, stream>>>(bufA, dinv, ptr, csr, bufB, n);
    // layer 3 (64-wide)
    gemm_kernel<64><<<g64, 256, 0, stream>>>(bufB, W3, b2, dinv, bufA, n);
    gather_kernel<64><<<gath_grid, 256, 0, stream>>>(bufA, dinv, ptr, csr, bufB, n);

    // fused relu(+b3) -> mean pool -> MLP
    pool_mlp_kernel<<<NGRAPH, 256, 0, stream>>>(bufB, b3, batch, Wf1, bf1, Wf2, bf2, out, n);
}

// Round 6
// 418.696 us; speedup vs baseline: 4.3010x; 1.1225x over previous
//
#include <hip/hip_runtime.h>
#include <hip/hip_fp16.h>

// GCN: 3x (GEMM -> normalized adjacency aggregate) + mean-pool + MLP.
// R2: atomic scatter -> CSR build + per-node gather (no float atomics).
// R3: hierarchical scan.  R4: register-tiled GEMM, CSR dispatch fusion.
// R5: gather MLP probe -> NEUTRAL: FETCH pinned at 186 MB = 25.6MB x 8 XCDs,
//     i.e. LLC-fill bandwidth bound (~3.2 TB/s), not latency bound.
// R6: hs staging buffer fp32 -> fp16: halves the mandatory per-XCD LLC fetch.
//     GEMM writes fp16 (fp32 accum), gather reads fp16 + accumulates fp32.
//   out[c] = dinv[c] * ( hs[c] + sum_{(r->c)} hs[r] ),  hs = (X@W) * dinv[row]

#define NGRAPH 100

// ---------------- degree histogram (int) ----------------

__global__ void deg_kernel(const int* __restrict__ col, int* __restrict__ cnt, int E) {
    int e = blockIdx.x * blockDim.x + threadIdx.x;
    if (e < E) atomicAdd(&cnt[col[e]], 1);
}

// ---------------- hierarchical exclusive scan: cnt[0..n) -> ptr[0..n] ----------------

__global__ __launch_bounds__(256) void scan_part1(const int* __restrict__ cnt,
                                                  int* __restrict__ bsum, int n) {
    __shared__ int ts[256];
    const int b = blockIdx.x, t = threadIdx.x;
    const int base = b * 1024 + t * 4;
    int s = 0;
    if (base + 3 < n) { int4 q = *(const int4*)&cnt[base]; s = q.x + q.y + q.z + q.w; }
    else { for (int i = 0; i < 4; ++i) if (base + i < n) s += cnt[base + i]; }
    ts[t] = s;
    __syncthreads();
    for (int off = 128; off > 0; off >>= 1) {
        if (t < off) ts[t] += ts[t + off];
        __syncthreads();
    }
    if (t == 0) bsum[b] = ts[0];
}

__global__ __launch_bounds__(256) void scan_part2(int* __restrict__ bsum, int nblk) {
    __shared__ int ts[256];
    const int t = threadIdx.x;
    int v = (t < nblk) ? bsum[t] : 0;
    ts[t] = v;
    __syncthreads();
    for (int off = 1; off < 256; off <<= 1) {
        int x = (t >= off) ? ts[t - off] : 0;
        __syncthreads();
        ts[t] += x;
        __syncthreads();
    }
    if (t < nblk) bsum[t] = ts[t] - v;   // exclusive
}

// pass 3: re-scan chunk + offset -> ptr; also cursor init (= ptr) and dinv.

__global__ __launch_bounds__(256) void scan_part3(const int* __restrict__ cnt,
                                                  const int* __restrict__ bsum,
                                                  int* __restrict__ ptr,
                                                  int* __restrict__ cursor,
                                                  float* __restrict__ dinv,
                                                  int n, int E) {
    __shared__ int ts[256];
    const int b = blockIdx.x, t = threadIdx.x;
    const int base = b * 1024 + t * 4;
    int v0 = 0, v1 = 0, v2 = 0, v3 = 0;
    if (base + 3 < n) {
        int4 q = *(const int4*)&cnt[base]; v0 = q.x; v1 = q.y; v2 = q.z; v3 = q.w;
    } else {
        if (base     < n) v0 = cnt[base];
        if (base + 1 < n) v1 = cnt[base + 1];
        if (base + 2 < n) v2 = cnt[base + 2];
        if (base + 3 < n) v3 = cnt[base + 3];
    }
    const int s = v0 + v1 + v2 + v3;
    ts[t] = s;
    __syncthreads();
    for (int off = 1; off < 256; off <<= 1) {
        int x = (t >= off) ? ts[t - off] : 0;
        __syncthreads();
        ts[t] += x;
        __syncthreads();
    }
    int e0 = ts[t] - s + bsum[b];
    int e1 = e0 + v0, e2 = e1 + v1, e3 = e2 + v2;
    if (base < n) {
        ptr[base] = e0; cursor[base] = e0;
        dinv[base] = 1.0f / sqrtf((float)(v0 + 1));
    }
    if (base + 1 < n) {
        ptr[base + 1] = e1; cursor[base + 1] = e1;
        dinv[base + 1] = 1.0f / sqrtf((float)(v1 + 1));
    }
    if (base + 2 < n) {
        ptr[base + 2] = e2; cursor[base + 2] = e2;
        dinv[base + 2] = 1.0f / sqrtf((float)(v2 + 1));
    }
    if (base + 3 < n) {
        ptr[base + 3] = e3; cursor[base + 3] = e3;
        dinv[base + 3] = 1.0f / sqrtf((float)(v3 + 1));
    }
    if (b == (int)gridDim.x - 1 && t == 255) ptr[n] = E;
}

// ---------------- CSR fill: csr[cursor[c]++] = row[e] (cursor pre-seeded with ptr) ----

__global__ void fill_kernel(const int* __restrict__ row, const int* __restrict__ col,
                            int* __restrict__ cursor, int* __restrict__ csr, int E) {
    int e = blockIdx.x * blockDim.x + threadIdx.x;
    if (e < E) {
        int pos = atomicAdd(&cursor[col[e]], 1);
        csr[pos] = row[e];
    }
}

// ---------------- GEMM: Yh[n,OUT](fp16) = transform(X[n,128]) @ W[128,OUT] * dinv[row] ----
// Register-tiled: thread computes 4 rows x 8 cols; W k-sliced (32) in LDS.
// transform(v,k) = bias_in ? relu(v + bias_in[k]) : v   (fuses prev layer's bias+relu)

template <int OUT>
__global__ __launch_bounds__(256) void gemm_kernel(const float* __restrict__ X,
                                                   const float* __restrict__ W,
                                                   const float* __restrict__ bias_in,
                                                   const float* __restrict__ dinv,
                                                   __half* __restrict__ Yh, int n) {
    constexpr int CG = OUT / 8;       // col groups of 8 (16 or 8)
    constexpr int RG = 256 / CG;      // row groups (16 or 32)
    constexpr int R  = RG * 4;        // rows per block (64 or 128)
    __shared__ float Ws[32 * OUT];    // W k-slice
    __shared__ float Xs[R * 32];      // X row-tile k-slice
    __shared__ float bs[128];

    const int t = threadIdx.x;
    if (t < 128) bs[t] = (bias_in != nullptr) ? bias_in[t] : 0.0f;
    __syncthreads();

    const int cg = t % CG;
    const int rg = t / CG;
    const int row0 = blockIdx.x * R;
    const bool do_relu = (bias_in != nullptr);

    float acc[4][8];
    #pragma unroll
    for (int i = 0; i < 4; ++i)
        #pragma unroll
        for (int j = 0; j < 8; ++j) acc[i][j] = 0.0f;

    for (int ks = 0; ks < 128; ks += 32) {
        for (int i = t * 4; i < 32 * OUT; i += 1024)
            *(float4*)&Ws[i] = *(const float4*)&W[ks * OUT + i];
        for (int i = t; i < R * 8; i += 256) {
            int r = i / 8, f4 = (i % 8) * 4;
            int gr = row0 + r;
            float4 v = make_float4(0.f, 0.f, 0.f, 0.f);
            if (gr < n) v = *(const float4*)&X[(size_t)gr * 128 + ks + f4];
            if (do_relu) {
                int k = ks + f4;
                v.x = fmaxf(v.x + bs[k + 0], 0.f);
                v.y = fmaxf(v.y + bs[k + 1], 0.f);
                v.z = fmaxf(v.z + bs[k + 2], 0.f);
                v.w = fmaxf(v.w + bs[k + 3], 0.f);
            }
            *(float4*)&Xs[r * 32 + f4] = v;
        }
        __syncthreads();

        #pragma unroll
        for (int kk = 0; kk < 32; kk += 4) {
            float xr[4][4];
            #pragma unroll
            for (int i = 0; i < 4; ++i) {
                float4 tv = *(const float4*)&Xs[(rg * 4 + i) * 32 + kk];
                xr[i][0] = tv.x; xr[i][1] = tv.y; xr[i][2] = tv.z; xr[i][3] = tv.w;
            }
            #pragma unroll
            for (int j = 0; j < 4; ++j) {
                float4 wa = *(const float4*)&Ws[(kk + j) * OUT + cg * 8];
                float4 wb = *(const float4*)&Ws[(kk + j) * OUT + cg * 8 + 4];
                #pragma unroll
                for (int i = 0; i < 4; ++i) {
                    float xv = xr[i][j];
                    acc[i][0] += xv * wa.x; acc[i][1] += xv * wa.y;
                    acc[i][2] += xv * wa.z; acc[i][3] += xv * wa.w;
                    acc[i][4] += xv * wb.x; acc[i][5] += xv * wb.y;
                    acc[i][6] += xv * wb.z; acc[i][7] += xv * wb.w;
                }
            }
        }
        __syncthreads();
    }

    // epilogue: scale by dinv[row], convert to fp16, 16B store
    #pragma unroll
    for (int i = 0; i < 4; ++i) {
        int gr = row0 + rg * 4 + i;
        if (gr < n) {
            float dw = dinv[gr];
            __half2 p0 = __float22half2_rn(make_float2(acc[i][0] * dw, acc[i][1] * dw));
            __half2 p1 = __float22half2_rn(make_float2(acc[i][2] * dw, acc[i][3] * dw));
            __half2 p2 = __float22half2_rn(make_float2(acc[i][4] * dw, acc[i][5] * dw));
            __half2 p3 = __float22half2_rn(make_float2(acc[i][6] * dw, acc[i][7] * dw));
            float4 pk;
            ((__half2*)&pk)[0] = p0; ((__half2*)&pk)[1] = p1;
            ((__half2*)&pk)[2] = p2; ((__half2*)&pk)[3] = p3;
            *(float4*)&Yh[(size_t)gr * OUT + cg * 8] = pk;
        }
    }
}

// ---------------- gather: out[c,:] = dinv[c] * (hs[c,:] + sum_in hs[src,:]) ----------------
// hs is fp16 (row = F halfs); accumulate fp32; out fp32.
// F=128: 2 half-wave streams, 32 lanes x 8B (4 halfs) per row.
// F=64:  4 quarter-wave streams, 16 lanes x 8B per row.

template <int F>
__global__ void gather_kernel(const __half* __restrict__ hs, const float* __restrict__ dinv,
                              const int* __restrict__ ptr, const int* __restrict__ csr,
                              float* __restrict__ out, int n) {
    const int lane = threadIdx.x & 63;
    const int c = (blockIdx.x * blockDim.x + threadIdx.x) >> 6;
    if (c >= n) return;
    const int beg = ptr[c], end = ptr[c + 1];
    const float w = dinv[c];
    const float2* hq = (const float2*)hs;    // 4 halfs per float2 (8B)

    auto cvt = [](float2 raw) {
        __half2 ha = *(__half2*)&raw.x;
        __half2 hb = *(__half2*)&raw.y;
        float2 fa = __half22float2(ha);
        float2 fb = __half22float2(hb);
        return make_float4(fa.x, fa.y, fb.x, fb.y);
    };

    if (F == 128) {
        const int half = lane >> 5;          // edge stream id
        const int l    = lane & 31;          // 8B-chunk index within row (32 x 8B = 256B)
        float4 acc = make_float4(0.f, 0.f, 0.f, 0.f);
        if (half == 0) {
            float4 v = cvt(hq[(size_t)c * 32 + l]);          // self-loop (once)
            acc = v;
        }
        int j = beg + half;
        for (; j + 6 < end; j += 8) {
            int s0 = csr[j], s1 = csr[j + 2], s2 = csr[j + 4], s3 = csr[j + 6];
            float4 v0 = cvt(hq[(size_t)s0 * 32 + l]);
            float4 v1 = cvt(hq[(size_t)s1 * 32 + l]);
            float4 v2 = cvt(hq[(size_t)s2 * 32 + l]);
            float4 v3 = cvt(hq[(size_t)s3 * 32 + l]);
            acc.x += v0.x + v1.x + v2.x + v3.x;
            acc.y += v0.y + v1.y + v2.y + v3.y;
            acc.z += v0.z + v1.z + v2.z + v3.z;
            acc.w += v0.w + v1.w + v2.w + v3.w;
        }
        for (; j < end; j += 2) {
            float4 v = cvt(hq[(size_t)csr[j] * 32 + l]);
            acc.x += v.x; acc.y += v.y; acc.z += v.z; acc.w += v.w;
        }
        acc.x += __shfl(acc.x, lane ^ 32);
        acc.y += __shfl(acc.y, lane ^ 32);
        acc.z += __shfl(acc.z, lane ^ 32);
        acc.w += __shfl(acc.w, lane ^ 32);
        if (half == 0) {
            float4 o = make_float4(w * acc.x, w * acc.y, w * acc.z, w * acc.w);
            ((float4*)out)[(size_t)c * 32 + l] = o;       // features l*4..l*4+3
        }
    } else {     // F == 64
        const int q = lane >> 4;             // stream id 0..3
        const int l = lane & 15;             // 8B-chunk index (16 x 8B = 128B)
        float4 acc = make_float4(0.f, 0.f, 0.f, 0.f);
        if (q == 0) acc = cvt(hq[(size_t)c * 16 + l]);       // self-loop (once)
        int j = beg + q;
        for (; j + 12 < end; j += 16) {
            int s0 = csr[j], s1 = csr[j + 4], s2 = csr[j + 8], s3 = csr[j + 12];
            float4 v0 = cvt(hq[(size_t)s0 * 16 + l]);
            float4 v1 = cvt(hq[(size_t)s1 * 16 + l]);
            float4 v2 = cvt(hq[(size_t)s2 * 16 + l]);
            float4 v3 = cvt(hq[(size_t)s3 * 16 + l]);
            acc.x += v0.x + v1.x + v2.x + v3.x;
            acc.y += v0.y + v1.y + v2.y + v3.y;
            acc.z += v0.z + v1.z + v2.z + v3.z;
            acc.w += v0.w + v1.w + v2.w + v3.w;
        }
        for (; j < end; j += 4) {
            float4 v = cvt(hq[(size_t)csr[j] * 16 + l]);
            acc.x += v.x; acc.y += v.y; acc.z += v.z; acc.w += v.w;
        }
        acc.x += __shfl(acc.x, lane ^ 16);
        acc.y += __shfl(acc.y, lane ^ 16);
        acc.z += __shfl(acc.z, lane ^ 16);
        acc.w += __shfl(acc.w, lane ^ 16);
        acc.x += __shfl(acc.x, lane ^ 32);
        acc.y += __shfl(acc.y, lane ^ 32);
        acc.z += __shfl(acc.z, lane ^ 32);
        acc.w += __shfl(acc.w, lane ^ 32);
        if (q == 0) {
            float4 o = make_float4(w * acc.x, w * acc.y, w * acc.z, w * acc.w);
            ((float4*)out)[(size_t)c * 16 + l] = o;
        }
    }
}

// ---------------- fused mean-pool + MLP head ----------------

__global__ void pool_mlp_kernel(const float* __restrict__ h, const float* __restrict__ b3,
                                const int* __restrict__ batch,
                                const float* __restrict__ Wf1, const float* __restrict__ bf1,
                                const float* __restrict__ Wf2, const float* __restrict__ bf2,
                                float* __restrict__ out, int n) {
    const int g = blockIdx.x;
    const int t = threadIdx.x;

    auto lb = [&](int v) {
        int lo = 0, hi = n;
        while (lo < hi) { int mid = (lo + hi) >> 1; if (batch[mid] < v) lo = mid + 1; else hi = mid; }
        return lo;
    };
    const int start = lb(g);
    const int end   = lb(g + 1);

    __shared__ float part[4][64];
    __shared__ float pooled[64];
    __shared__ float hid[32];

    const int f = t & 63, sub = t >> 6;
    const float bias = b3[f];
    float acc = 0.f;
    for (int i = start + sub; i < end; i += 4)
        acc += fmaxf(h[(size_t)i * 64 + f] + bias, 0.f);
    part[sub][f] = acc;
    __syncthreads();

    if (t < 64) {
        float s = part[0][t] + part[1][t] + part[2][t] + part[3][t];
        int cnt = end - start;
        pooled[t] = s / (float)(cnt > 0 ? cnt : 1);
    }
    __syncthreads();

    if (t < 32) {
        float a = bf1[t];
        #pragma unroll
        for (int k = 0; k < 64; ++k) a += pooled[k] * Wf1[k * 32 + t];
        hid[t] = fmaxf(a, 0.f);
    }
    __syncthreads();

    if (t < 10) {
        float a = bf2[t];
        #pragma unroll
        for (int k = 0; k < 32; ++k) a += hid[k] * Wf2[k * 10 + t];
        out[g * 10 + t] = a;
    }
}

// ---------------- launcher ----------------

extern "C" void kernel_launch(void* const* d_in, const int* in_sizes, int n_in,
                              void* d_out, int out_size, void* d_ws, size_t ws_size,
                              hipStream_t stream) {
    const float* x     = (const float*)d_in[0];
    const int*   edge  = (const int*)  d_in[1];
    const int*   batch = (const int*)  d_in[2];
    const float* W1    = (const float*)d_in[3];
    const float* b1    = (const float*)d_in[4];
    const float* W2    = (const float*)d_in[5];
    const float* b2    = (const float*)d_in[6];
    const float* W3    = (const float*)d_in[7];
    const float* b3    = (const float*)d_in[8];
    const float* Wf1   = (const float*)d_in[9];
    const float* bf1   = (const float*)d_in[10];
    const float* Wf2   = (const float*)d_in[11];
    const float* bf2   = (const float*)d_in[12];
    float* out = (float*)d_out;

    const int E = in_sizes[1] / 2;     // 800000
    const int n = in_sizes[2];         // 50000
    const int* row = edge;
    const int* col = edge + E;

    const int nblk = (n + 1023) / 1024;                    // scan chunks (49)

    const size_t n_pad = ((size_t)n + 64) & ~(size_t)63;   // >= n+1, 64-aligned
    char* wsb = (char*)d_ws;
    int*    cnt  = (int*)wsb;                    wsb += n_pad * 4;   // reused as cursor
    int*    ptr  = (int*)wsb;                    wsb += n_pad * 4;
    float*  dinv = (float*)wsb;                  wsb += n_pad * 4;
    int*    bsum = (int*)wsb;                    wsb += 256 * 4;
    int*    csr  = (int*)wsb;                    wsb += (((size_t)E + 63) & ~(size_t)63) * 4;
    __half* bufA = (__half*)wsb;                 wsb += (size_t)n * 128 * 2;   // fp16 hs
    float*  bufB = (float*)wsb;

    // ---- CSR build (once, reused for all 3 layers) ----
    hipMemsetAsync(cnt, 0, (size_t)n * 4, stream);
    deg_kernel<<<(E + 255) / 256, 256, 0, stream>>>(col, cnt, E);
    scan_part1<<<nblk, 256, 0, stream>>>(cnt, bsum, n);
    scan_part2<<<1, 256, 0, stream>>>(bsum, nblk);
    scan_part3<<<nblk, 256, 0, stream>>>(cnt, bsum, ptr, cnt, dinv, n, E);  // cursor aliases cnt
    fill_kernel<<<(E + 255) / 256, 256, 0, stream>>>(row, col, cnt, csr, E);

    const int g128 = (n + 63) / 64;    // gemm<128> blocks (64 rows each)
    const int g64  = (n + 127) / 128;  // gemm<64>  blocks (128 rows each)
    const int gath_grid = (n * 64 + 255) / 256;            // one wave per node

    // layer 1
    gemm_kernel<128><<<g128, 256, 0, stream>>>(x, W1, nullptr, dinv, bufA, n);
    gather_kernel<128><<<gath_grid, 256, 0, stream>>>(bufA, dinv, ptr, csr, bufB, n);
    // layer 2
    gemm_kernel<128><<<g128, 256, 0, stream>>>(bufB, W2, b1, dinv, bufA, n);
    gather_kernel<128><<<gath_grid, 256, 0, stream>>>(bufA, dinv, ptr, csr, bufB, n);
    // layer 3 (64-wide)
    gemm_kernel<64><<<g64, 256, 0, stream>>>(bufB, W3, b2, dinv, bufA, n);
    gather_kernel<64><<<gath_grid, 256, 0, stream>>>(bufA, dinv, ptr, csr, bufB, n);

    // fused relu(+b3) -> mean pool -> MLP
    pool_mlp_kernel<<<NGRAPH, 256, 0, stream>>>(bufB, b3, batch, Wf1, bf1, Wf2, bf2, out, n);
}

// Round 7
// 408.616 us; speedup vs baseline: 4.4071x; 1.0247x over previous
//
#include <hip/hip_runtime.h>
#include <hip/hip_fp16.h>

// GCN: 3x (GEMM -> normalized adjacency aggregate) + mean-pool + MLP.
// R2: atomic scatter -> CSR build + per-node gather (no float atomics).
// R3: hierarchical scan.  R4: register-tiled GEMM, CSR dispatch fusion.
// R5: gather MLP probe -> NEUTRAL: gather is LLC-fill-BW bound (186MB = 25.6MB x 8 XCD).
// R6: hs staging fp32 -> fp16 (halves mandatory per-XCD fetch). 470 -> 419 us.
// R7: col-partitioned fill/deg: 8 block-groups (blockIdx&7 ~ XCD round-robin),
//     group g only handles cols in its n/8 range -> csr writes land in a ~400KB
//     L2-resident window -> write-combining (WRITE 52MB -> ~5MB predicted).
//   out[c] = dinv[c] * ( hs[c] + sum_{(r->c)} hs[r] ),  hs = (X@W) * dinv[row]

#define NGRAPH 100

// ---------------- degree histogram (int), col-partitioned ----------------

__global__ void deg_kernel(const int* __restrict__ col, int* __restrict__ cnt,
                           int E, int colsPerGroup) {
    const int g  = blockIdx.x & 7;
    const int gb = blockIdx.x >> 3;
    const int nb = gridDim.x >> 3;
    const int lo = g * colsPerGroup, hi = lo + colsPerGroup;
    for (int e = gb * 256 + threadIdx.x; e < E; e += nb * 256) {
        int c = col[e];
        if (c >= lo && c < hi) atomicAdd(&cnt[c], 1);
    }
}

// ---------------- hierarchical exclusive scan: cnt[0..n) -> ptr[0..n] ----------------

__global__ __launch_bounds__(256) void scan_part1(const int* __restrict__ cnt,
                                                  int* __restrict__ bsum, int n) {
    __shared__ int ts[256];
    const int b = blockIdx.x, t = threadIdx.x;
    const int base = b * 1024 + t * 4;
    int s = 0;
    if (base + 3 < n) { int4 q = *(const int4*)&cnt[base]; s = q.x + q.y + q.z + q.w; }
    else { for (int i = 0; i < 4; ++i) if (base + i < n) s += cnt[base + i]; }
    ts[t] = s;
    __syncthreads();
    for (int off = 128; off > 0; off >>= 1) {
        if (t < off) ts[t] += ts[t + off];
        __syncthreads();
    }
    if (t == 0) bsum[b] = ts[0];
}

__global__ __launch_bounds__(256) void scan_part2(int* __restrict__ bsum, int nblk) {
    __shared__ int ts[256];
    const int t = threadIdx.x;
    int v = (t < nblk) ? bsum[t] : 0;
    ts[t] = v;
    __syncthreads();
    for (int off = 1; off < 256; off <<= 1) {
        int x = (t >= off) ? ts[t - off] : 0;
        __syncthreads();
        ts[t] += x;
        __syncthreads();
    }
    if (t < nblk) bsum[t] = ts[t] - v;   // exclusive
}

// pass 3: re-scan chunk + offset -> ptr; also cursor init (= ptr) and dinv.

__global__ __launch_bounds__(256) void scan_part3(const int* __restrict__ cnt,
                                                  const int* __restrict__ bsum,
                                                  int* __restrict__ ptr,
                                                  int* __restrict__ cursor,
                                                  float* __restrict__ dinv,
                                                  int n, int E) {
    __shared__ int ts[256];
    const int b = blockIdx.x, t = threadIdx.x;
    const int base = b * 1024 + t * 4;
    int v0 = 0, v1 = 0, v2 = 0, v3 = 0;
    if (base + 3 < n) {
        int4 q = *(const int4*)&cnt[base]; v0 = q.x; v1 = q.y; v2 = q.z; v3 = q.w;
    } else {
        if (base     < n) v0 = cnt[base];
        if (base + 1 < n) v1 = cnt[base + 1];
        if (base + 2 < n) v2 = cnt[base + 2];
        if (base + 3 < n) v3 = cnt[base + 3];
    }
    const int s = v0 + v1 + v2 + v3;
    ts[t] = s;
    __syncthreads();
    for (int off = 1; off < 256; off <<= 1) {
        int x = (t >= off) ? ts[t - off] : 0;
        __syncthreads();
        ts[t] += x;
        __syncthreads();
    }
    int e0 = ts[t] - s + bsum[b];
    int e1 = e0 + v0, e2 = e1 + v1, e3 = e2 + v2;
    if (base < n) {
        ptr[base] = e0; cursor[base] = e0;
        dinv[base] = 1.0f / sqrtf((float)(v0 + 1));
    }
    if (base + 1 < n) {
        ptr[base + 1] = e1; cursor[base + 1] = e1;
        dinv[base + 1] = 1.0f / sqrtf((float)(v1 + 1));
    }
    if (base + 2 < n) {
        ptr[base + 2] = e2; cursor[base + 2] = e2;
        dinv[base + 2] = 1.0f / sqrtf((float)(v2 + 1));
    }
    if (base + 3 < n) {
        ptr[base + 3] = e3; cursor[base + 3] = e3;
        dinv[base + 3] = 1.0f / sqrtf((float)(v3 + 1));
    }
    if (b == (int)gridDim.x - 1 && t == 255) ptr[n] = E;
}

// ---------------- CSR fill, col-partitioned: csr[cursor[c]++] = row[e] ----------------
// Group g (blockIdx&7) only claims edges with col in its range; its csr writes
// fall in one contiguous ~E/8 window -> L2 write-combining. Edge set partition
// is by VALUE (col), so correctness is independent of block->XCD mapping.

__global__ void fill_kernel(const int* __restrict__ row, const int* __restrict__ col,
                            int* __restrict__ cursor, int* __restrict__ csr,
                            int E, int colsPerGroup) {
    const int g  = blockIdx.x & 7;
    const int gb = blockIdx.x >> 3;
    const int nb = gridDim.x >> 3;
    const int lo = g * colsPerGroup, hi = lo + colsPerGroup;
    for (int e = gb * 256 + threadIdx.x; e < E; e += nb * 256) {
        int c = col[e];
        if (c >= lo && c < hi) {
            int pos = atomicAdd(&cursor[c], 1);
            csr[pos] = row[e];
        }
    }
}

// ---------------- GEMM: Yh[n,OUT](fp16) = transform(X[n,128]) @ W[128,OUT] * dinv[row] ----

template <int OUT>
__global__ __launch_bounds__(256) void gemm_kernel(const float* __restrict__ X,
                                                   const float* __restrict__ W,
                                                   const float* __restrict__ bias_in,
                                                   const float* __restrict__ dinv,
                                                   __half* __restrict__ Yh, int n) {
    constexpr int CG = OUT / 8;
    constexpr int RG = 256 / CG;
    constexpr int R  = RG * 4;
    __shared__ float Ws[32 * OUT];
    __shared__ float Xs[R * 32];
    __shared__ float bs[128];

    const int t = threadIdx.x;
    if (t < 128) bs[t] = (bias_in != nullptr) ? bias_in[t] : 0.0f;
    __syncthreads();

    const int cg = t % CG;
    const int rg = t / CG;
    const int row0 = blockIdx.x * R;
    const bool do_relu = (bias_in != nullptr);

    float acc[4][8];
    #pragma unroll
    for (int i = 0; i < 4; ++i)
        #pragma unroll
        for (int j = 0; j < 8; ++j) acc[i][j] = 0.0f;

    for (int ks = 0; ks < 128; ks += 32) {
        for (int i = t * 4; i < 32 * OUT; i += 1024)
            *(float4*)&Ws[i] = *(const float4*)&W[ks * OUT + i];
        for (int i = t; i < R * 8; i += 256) {
            int r = i / 8, f4 = (i % 8) * 4;
            int gr = row0 + r;
            float4 v = make_float4(0.f, 0.f, 0.f, 0.f);
            if (gr < n) v = *(const float4*)&X[(size_t)gr * 128 + ks + f4];
            if (do_relu) {
                int k = ks + f4;
                v.x = fmaxf(v.x + bs[k + 0], 0.f);
                v.y = fmaxf(v.y + bs[k + 1], 0.f);
                v.z = fmaxf(v.z + bs[k + 2], 0.f);
                v.w = fmaxf(v.w + bs[k + 3], 0.f);
            }
            *(float4*)&Xs[r * 32 + f4] = v;
        }
        __syncthreads();

        #pragma unroll
        for (int kk = 0; kk < 32; kk += 4) {
            float xr[4][4];
            #pragma unroll
            for (int i = 0; i < 4; ++i) {
                float4 tv = *(const float4*)&Xs[(rg * 4 + i) * 32 + kk];
                xr[i][0] = tv.x; xr[i][1] = tv.y; xr[i][2] = tv.z; xr[i][3] = tv.w;
            }
            #pragma unroll
            for (int j = 0; j < 4; ++j) {
                float4 wa = *(const float4*)&Ws[(kk + j) * OUT + cg * 8];
                float4 wb = *(const float4*)&Ws[(kk + j) * OUT + cg * 8 + 4];
                #pragma unroll
                for (int i = 0; i < 4; ++i) {
                    float xv = xr[i][j];
                    acc[i][0] += xv * wa.x; acc[i][1] += xv * wa.y;
                    acc[i][2] += xv * wa.z; acc[i][3] += xv * wa.w;
                    acc[i][4] += xv * wb.x; acc[i][5] += xv * wb.y;
                    acc[i][6] += xv * wb.z; acc[i][7] += xv * wb.w;
                }
            }
        }
        __syncthreads();
    }

    #pragma unroll
    for (int i = 0; i < 4; ++i) {
        int gr = row0 + rg * 4 + i;
        if (gr < n) {
            float dw = dinv[gr];
            __half2 p0 = __float22half2_rn(make_float2(acc[i][0] * dw, acc[i][1] * dw));
            __half2 p1 = __float22half2_rn(make_float2(acc[i][2] * dw, acc[i][3] * dw));
            __half2 p2 = __float22half2_rn(make_float2(acc[i][4] * dw, acc[i][5] * dw));
            __half2 p3 = __float22half2_rn(make_float2(acc[i][6] * dw, acc[i][7] * dw));
            float4 pk;
            ((__half2*)&pk)[0] = p0; ((__half2*)&pk)[1] = p1;
            ((__half2*)&pk)[2] = p2; ((__half2*)&pk)[3] = p3;
            *(float4*)&Yh[(size_t)gr * OUT + cg * 8] = pk;
        }
    }
}

// ---------------- gather: out[c,:] = dinv[c] * (hs[c,:] + sum_in hs[src,:]) ----------------

template <int F>
__global__ void gather_kernel(const __half* __restrict__ hs, const float* __restrict__ dinv,
                              const int* __restrict__ ptr, const int* __restrict__ csr,
                              float* __restrict__ out, int n) {
    const int lane = threadIdx.x & 63;
    const int c = (blockIdx.x * blockDim.x + threadIdx.x) >> 6;
    if (c >= n) return;
    const int beg = ptr[c], end = ptr[c + 1];
    const float w = dinv[c];
    const float2* hq = (const float2*)hs;

    auto cvt = [](float2 raw) {
        __half2 ha = *(__half2*)&raw.x;
        __half2 hb = *(__half2*)&raw.y;
        float2 fa = __half22float2(ha);
        float2 fb = __half22float2(hb);
        return make_float4(fa.x, fa.y, fb.x, fb.y);
    };

    if (F == 128) {
        const int half = lane >> 5;
        const int l    = lane & 31;
        float4 acc = make_float4(0.f, 0.f, 0.f, 0.f);
        if (half == 0) acc = cvt(hq[(size_t)c * 32 + l]);
        int j = beg + half;
        for (; j + 6 < end; j += 8) {
            int s0 = csr[j], s1 = csr[j + 2], s2 = csr[j + 4], s3 = csr[j + 6];
            float4 v0 = cvt(hq[(size_t)s0 * 32 + l]);
            float4 v1 = cvt(hq[(size_t)s1 * 32 + l]);
            float4 v2 = cvt(hq[(size_t)s2 * 32 + l]);
            float4 v3 = cvt(hq[(size_t)s3 * 32 + l]);
            acc.x += v0.x + v1.x + v2.x + v3.x;
            acc.y += v0.y + v1.y + v2.y + v3.y;
            acc.z += v0.z + v1.z + v2.z + v3.z;
            acc.w += v0.w + v1.w + v2.w + v3.w;
        }
        for (; j < end; j += 2) {
            float4 v = cvt(hq[(size_t)csr[j] * 32 + l]);
            acc.x += v.x; acc.y += v.y; acc.z += v.z; acc.w += v.w;
        }
        acc.x += __shfl(acc.x, lane ^ 32);
        acc.y += __shfl(acc.y, lane ^ 32);
        acc.z += __shfl(acc.z, lane ^ 32);
        acc.w += __shfl(acc.w, lane ^ 32);
        if (half == 0) {
            float4 o = make_float4(w * acc.x, w * acc.y, w * acc.z, w * acc.w);
            ((float4*)out)[(size_t)c * 32 + l] = o;
        }
    } else {     // F == 64
        const int q = lane >> 4;
        const int l = lane & 15;
        float4 acc = make_float4(0.f, 0.f, 0.f, 0.f);
        if (q == 0) acc = cvt(hq[(size_t)c * 16 + l]);
        int j = beg + q;
        for (; j + 12 < end; j += 16) {
            int s0 = csr[j], s1 = csr[j + 4], s2 = csr[j + 8], s3 = csr[j + 12];
            float4 v0 = cvt(hq[(size_t)s0 * 16 + l]);
            float4 v1 = cvt(hq[(size_t)s1 * 16 + l]);
            float4 v2 = cvt(hq[(size_t)s2 * 16 + l]);
            float4 v3 = cvt(hq[(size_t)s3 * 16 + l]);
            acc.x += v0.x + v1.x + v2.x + v3.x;
            acc.y += v0.y + v1.y + v2.y + v3.y;
            acc.z += v0.z + v1.z + v2.z + v3.z;
            acc.w += v0.w + v1.w + v2.w + v3.w;
        }
        for (; j < end; j += 4) {
            float4 v = cvt(hq[(size_t)csr[j] * 16 + l]);
            acc.x += v.x; acc.y += v.y; acc.z += v.z; acc.w += v.w;
        }
        acc.x += __shfl(acc.x, lane ^ 16);
        acc.y += __shfl(acc.y, lane ^ 16);
        acc.z += __shfl(acc.z, lane ^ 16);
        acc.w += __shfl(acc.w, lane ^ 16);
        acc.x += __shfl(acc.x, lane ^ 32);
        acc.y += __shfl(acc.y, lane ^ 32);
        acc.z += __shfl(acc.z, lane ^ 32);
        acc.w += __shfl(acc.w, lane ^ 32);
        if (q == 0) {
            float4 o = make_float4(w * acc.x, w * acc.y, w * acc.z, w * acc.w);
            ((float4*)out)[(size_t)c * 16 + l] = o;
        }
    }
}

// ---------------- fused mean-pool + MLP head ----------------

__global__ void pool_mlp_kernel(const float* __restrict__ h, const float* __restrict__ b3,
                                const int* __restrict__ batch,
                                const float* __restrict__ Wf1, const float* __restrict__ bf1,
                                const float* __restrict__ Wf2, const float* __restrict__ bf2,
                                float* __restrict__ out, int n) {
    const int g = blockIdx.x;
    const int t = threadIdx.x;

    auto lb = [&](int v) {
        int lo = 0, hi = n;
        while (lo < hi) { int mid = (lo + hi) >> 1; if (batch[mid] < v) lo = mid + 1; else hi = mid; }
        return lo;
    };
    const int start = lb(g);
    const int end   = lb(g + 1);

    __shared__ float part[4][64];
    __shared__ float pooled[64];
    __shared__ float hid[32];

    const int f = t & 63, sub = t >> 6;
    const float bias = b3[f];
    float acc = 0.f;
    for (int i = start + sub; i < end; i += 4)
        acc += fmaxf(h[(size_t)i * 64 + f] + bias, 0.f);
    part[sub][f] = acc;
    __syncthreads();

    if (t < 64) {
        float s = part[0][t] + part[1][t] + part[2][t] + part[3][t];
        int cnt = end - start;
        pooled[t] = s / (float)(cnt > 0 ? cnt : 1);
    }
    __syncthreads();

    if (t < 32) {
        float a = bf1[t];
        #pragma unroll
        for (int k = 0; k < 64; ++k) a += pooled[k] * Wf1[k * 32 + t];
        hid[t] = fmaxf(a, 0.f);
    }
    __syncthreads();

    if (t < 10) {
        float a = bf2[t];
        #pragma unroll
        for (int k = 0; k < 32; ++k) a += hid[k] * Wf2[k * 10 + t];
        out[g * 10 + t] = a;
    }
}

// ---------------- launcher ----------------

extern "C" void kernel_launch(void* const* d_in, const int* in_sizes, int n_in,
                              void* d_out, int out_size, void* d_ws, size_t ws_size,
                              hipStream_t stream) {
    const float* x     = (const float*)d_in[0];
    const int*   edge  = (const int*)  d_in[1];
    const int*   batch = (const int*)  d_in[2];
    const float* W1    = (const float*)d_in[3];
    const float* b1    = (const float*)d_in[4];
    const float* W2    = (const float*)d_in[5];
    const float* b2    = (const float*)d_in[6];
    const float* W3    = (const float*)d_in[7];
    const float* b3    = (const float*)d_in[8];
    const float* Wf1   = (const float*)d_in[9];
    const float* bf1   = (const float*)d_in[10];
    const float* Wf2   = (const float*)d_in[11];
    const float* bf2   = (const float*)d_in[12];
    float* out = (float*)d_out;

    const int E = in_sizes[1] / 2;     // 800000
    const int n = in_sizes[2];         // 50000
    const int* row = edge;
    const int* col = edge + E;

    const int nblk = (n + 1023) / 1024;                    // scan chunks (49)
    const int colsPerGroup = (n + 7) / 8;                  // 6250

    const size_t n_pad = ((size_t)n + 64) & ~(size_t)63;   // >= n+1, 64-aligned
    char* wsb = (char*)d_ws;
    int*    cnt  = (int*)wsb;                    wsb += n_pad * 4;   // reused as cursor
    int*    ptr  = (int*)wsb;                    wsb += n_pad * 4;
    float*  dinv = (float*)wsb;                  wsb += n_pad * 4;
    int*    bsum = (int*)wsb;                    wsb += 256 * 4;
    int*    csr  = (int*)wsb;                    wsb += (((size_t)E + 63) & ~(size_t)63) * 4;
    __half* bufA = (__half*)wsb;                 wsb += (size_t)n * 128 * 2;   // fp16 hs
    float*  bufB = (float*)wsb;

    // ---- CSR build (once, reused for all 3 layers) ----
    hipMemsetAsync(cnt, 0, (size_t)n * 4, stream);
    deg_kernel<<<1024, 256, 0, stream>>>(col, cnt, E, colsPerGroup);
    scan_part1<<<nblk, 256, 0, stream>>>(cnt, bsum, n);
    scan_part2<<<1, 256, 0, stream>>>(bsum, nblk);
    scan_part3<<<nblk, 256, 0, stream>>>(cnt, bsum, ptr, cnt, dinv, n, E);  // cursor aliases cnt
    fill_kernel<<<1024, 256, 0, stream>>>(row, col, cnt, csr, E, colsPerGroup);

    const int g128 = (n + 63) / 64;    // gemm<128> blocks (64 rows each)
    const int g64  = (n + 127) / 128;  // gemm<64>  blocks (128 rows each)
    const int gath_grid = (n * 64 + 255) / 256;            // one wave per node

    // layer 1
    gemm_kernel<128><<<g128, 256, 0, stream>>>(x, W1, nullptr, dinv, bufA, n);
    gather_kernel<128><<<gath_grid, 256, 0, stream>>>(bufA, dinv, ptr, csr, bufB, n);
    // layer 2
    gemm_kernel<128><<<g128, 256, 0, stream>>>(bufB, W2, b1, dinv, bufA, n);
    gather_kernel<128><<<gath_grid, 256, 0, stream>>>(bufA, dinv, ptr, csr, bufB, n);
    // layer 3 (64-wide)
    gemm_kernel<64><<<g64, 256, 0, stream>>>(bufB, W3, b2, dinv, bufA, n);
    gather_kernel<64><<<gath_grid, 256, 0, stream>>>(bufA, dinv, ptr, csr, bufB, n);

    // fused relu(+b3) -> mean pool -> MLP
    pool_mlp_kernel<<<NGRAPH, 256, 0, stream>>>(bufB, b3, batch, Wf1, bf1, Wf2, bf2, out, n);
}

// Round 8
// 345.499 us; speedup vs baseline: 5.2122x; 1.1827x over previous
//
#include <hip/hip_runtime.h>
#include <hip/hip_fp16.h>

// GCN: 3x (GEMM -> normalized adjacency aggregate) + mean-pool + MLP.
// R2: atomic scatter -> CSR + gather.  R3: hierarchical scan.
// R4: register-tiled GEMM.  R5: MLP probe -> gather is LLC-fill-BW bound.
// R6: hs fp16 (halved gather fetch). 470->419.  R7: col-partitioned fill. ->409.
// R8: GEMM -> fp16 MFMA (mfma_f32_16x16x32_f16). fp32 VALU GEMM was LDS-bound
//     with 4-way bank conflicts (4.8M SQ_LDS_BANK_CONFLICT, 52us). Now:
//     W pre-transposed to fp16 Wt[n][k] once; X+Wt staged to LDS with XOR
//     chunk swizzle (conflict-free b128 frag reads); 4 waves x 16 rows/block.
//   out[c] = dinv[c] * ( hs[c] + sum_{(r->c)} hs[r] ),  hs = (X@W) * dinv[row]

#define NGRAPH 100

typedef _Float16 f16x8 __attribute__((ext_vector_type(8)));
typedef float f32x4 __attribute__((ext_vector_type(4)));

// ---------------- degree histogram (int), col-partitioned ----------------

__global__ void deg_kernel(const int* __restrict__ col, int* __restrict__ cnt,
                           int E, int colsPerGroup) {
    const int g  = blockIdx.x & 7;
    const int gb = blockIdx.x >> 3;
    const int nb = gridDim.x >> 3;
    const int lo = g * colsPerGroup, hi = lo + colsPerGroup;
    for (int e = gb * 256 + threadIdx.x; e < E; e += nb * 256) {
        int c = col[e];
        if (c >= lo && c < hi) atomicAdd(&cnt[c], 1);
    }
}

// ---------------- hierarchical exclusive scan: cnt[0..n) -> ptr[0..n] ----------------

__global__ __launch_bounds__(256) void scan_part1(const int* __restrict__ cnt,
                                                  int* __restrict__ bsum, int n) {
    __shared__ int ts[256];
    const int b = blockIdx.x, t = threadIdx.x;
    const int base = b * 1024 + t * 4;
    int s = 0;
    if (base + 3 < n) { int4 q = *(const int4*)&cnt[base]; s = q.x + q.y + q.z + q.w; }
    else { for (int i = 0; i < 4; ++i) if (base + i < n) s += cnt[base + i]; }
    ts[t] = s;
    __syncthreads();
    for (int off = 128; off > 0; off >>= 1) {
        if (t < off) ts[t] += ts[t + off];
        __syncthreads();
    }
    if (t == 0) bsum[b] = ts[0];
}

__global__ __launch_bounds__(256) void scan_part2(int* __restrict__ bsum, int nblk) {
    __shared__ int ts[256];
    const int t = threadIdx.x;
    int v = (t < nblk) ? bsum[t] : 0;
    ts[t] = v;
    __syncthreads();
    for (int off = 1; off < 256; off <<= 1) {
        int x = (t >= off) ? ts[t - off] : 0;
        __syncthreads();
        ts[t] += x;
        __syncthreads();
    }
    if (t < nblk) bsum[t] = ts[t] - v;   // exclusive
}

__global__ __launch_bounds__(256) void scan_part3(const int* __restrict__ cnt,
                                                  const int* __restrict__ bsum,
                                                  int* __restrict__ ptr,
                                                  int* __restrict__ cursor,
                                                  float* __restrict__ dinv,
                                                  int n, int E) {
    __shared__ int ts[256];
    const int b = blockIdx.x, t = threadIdx.x;
    const int base = b * 1024 + t * 4;
    int v0 = 0, v1 = 0, v2 = 0, v3 = 0;
    if (base + 3 < n) {
        int4 q = *(const int4*)&cnt[base]; v0 = q.x; v1 = q.y; v2 = q.z; v3 = q.w;
    } else {
        if (base     < n) v0 = cnt[base];
        if (base + 1 < n) v1 = cnt[base + 1];
        if (base + 2 < n) v2 = cnt[base + 2];
        if (base + 3 < n) v3 = cnt[base + 3];
    }
    const int s = v0 + v1 + v2 + v3;
    ts[t] = s;
    __syncthreads();
    for (int off = 1; off < 256; off <<= 1) {
        int x = (t >= off) ? ts[t - off] : 0;
        __syncthreads();
        ts[t] += x;
        __syncthreads();
    }
    int e0 = ts[t] - s + bsum[b];
    int e1 = e0 + v0, e2 = e1 + v1, e3 = e2 + v2;
    if (base < n) {
        ptr[base] = e0; cursor[base] = e0;
        dinv[base] = 1.0f / sqrtf((float)(v0 + 1));
    }
    if (base + 1 < n) {
        ptr[base + 1] = e1; cursor[base + 1] = e1;
        dinv[base + 1] = 1.0f / sqrtf((float)(v1 + 1));
    }
    if (base + 2 < n) {
        ptr[base + 2] = e2; cursor[base + 2] = e2;
        dinv[base + 2] = 1.0f / sqrtf((float)(v2 + 1));
    }
    if (base + 3 < n) {
        ptr[base + 3] = e3; cursor[base + 3] = e3;
        dinv[base + 3] = 1.0f / sqrtf((float)(v3 + 1));
    }
    if (b == (int)gridDim.x - 1 && t == 255) ptr[n] = E;
}

// ---------------- CSR fill, col-partitioned ----------------

__global__ void fill_kernel(const int* __restrict__ row, const int* __restrict__ col,
                            int* __restrict__ cursor, int* __restrict__ csr,
                            int E, int colsPerGroup) {
    const int g  = blockIdx.x & 7;
    const int gb = blockIdx.x >> 3;
    const int nb = gridDim.x >> 3;
    const int lo = g * colsPerGroup, hi = lo + colsPerGroup;
    for (int e = gb * 256 + threadIdx.x; e < E; e += nb * 256) {
        int c = col[e];
        if (c >= lo && c < hi) {
            int pos = atomicAdd(&cursor[c], 1);
            csr[pos] = row[e];
        }
    }
}

// ---------------- W prep: Wt[n][k] = (half)W[k][n] for W1,W2 (128x128), W3 (128x64) ----

__global__ void prep_w(const float* __restrict__ W1, const float* __restrict__ W2,
                       const float* __restrict__ W3,
                       __half* __restrict__ Wt1, __half* __restrict__ Wt2,
                       __half* __restrict__ Wt3) {
    int idx = blockIdx.x * 256 + threadIdx.x;
    if (idx < 16384) {                       // W1: n=idx>>7, k=idx&127
        int nn = idx >> 7, k = idx & 127;
        Wt1[idx] = __float2half(W1[k * 128 + nn]);
    } else if (idx < 32768) {                // W2
        int j = idx - 16384;
        int nn = j >> 7, k = j & 127;
        Wt2[j] = __float2half(W2[k * 128 + nn]);
    } else if (idx < 40960) {                // W3: 128x64 -> Wt3[n<64][k<128]
        int j = idx - 32768;
        int nn = j >> 7, k = j & 127;
        Wt3[j] = __float2half(W3[k * 64 + nn]);
    }
}

// ---------------- MFMA GEMM: Yh[n,OUT](fp16) = relu?(X + b) @ W * dinv[row] ----------
// Block: 256 thr / 4 waves; 64 rows/block; wave w owns rows w*16..w*16+15, all OUT cols.
// LDS swizzle: row r stored as 16 chunks of 8 halfs; chunk q lives at q ^ (r&15).
// Frag layouts (verified, guide §3): A/B [idx=lane&15][k=quad*8+j]; C/D col=lane&15,
// row=quad*4+reg.

template <int OUT>
__global__ __launch_bounds__(256) void gemm_mfma(const float* __restrict__ X,
                                                 const __half* __restrict__ Wt,
                                                 const float* __restrict__ bias_in,
                                                 const float* __restrict__ dinv,
                                                 __half* __restrict__ Yh, int n) {
    __shared__ _Float16 Xs[64 * 128];
    __shared__ _Float16 Ws[OUT * 128];
    __shared__ float bs[128];

    const int t = threadIdx.x;
    if (t < 128) bs[t] = (bias_in != nullptr) ? bias_in[t] : 0.0f;
    __syncthreads();

    const int row0 = blockIdx.x * 64;
    const bool do_relu = (bias_in != nullptr);

    // stage X: fp32 -> fp16 with fused bias+relu; swizzled 16B chunk writes
    for (int c = t; c < 64 * 16; c += 256) {
        const int r = c >> 4, q = c & 15;
        const int gr = row0 + r;
        float4 va = make_float4(0.f, 0.f, 0.f, 0.f), vb = va;
        if (gr < n) {
            va = *(const float4*)&X[(size_t)gr * 128 + q * 8];
            vb = *(const float4*)&X[(size_t)gr * 128 + q * 8 + 4];
        }
        if (do_relu) {
            const int k = q * 8;
            va.x = fmaxf(va.x + bs[k + 0], 0.f);
            va.y = fmaxf(va.y + bs[k + 1], 0.f);
            va.z = fmaxf(va.z + bs[k + 2], 0.f);
            va.w = fmaxf(va.w + bs[k + 3], 0.f);
            vb.x = fmaxf(vb.x + bs[k + 4], 0.f);
            vb.y = fmaxf(vb.y + bs[k + 5], 0.f);
            vb.z = fmaxf(vb.z + bs[k + 6], 0.f);
            vb.w = fmaxf(vb.w + bs[k + 7], 0.f);
        }
        f16x8 hv;
        hv[0] = (_Float16)va.x; hv[1] = (_Float16)va.y;
        hv[2] = (_Float16)va.z; hv[3] = (_Float16)va.w;
        hv[4] = (_Float16)vb.x; hv[5] = (_Float16)vb.y;
        hv[6] = (_Float16)vb.z; hv[7] = (_Float16)vb.w;
        *(f16x8*)&Xs[(size_t)((r << 4) + (q ^ (r & 15))) * 8] = hv;
    }
    // stage Wt (fp16 already): swizzled
    for (int c = t; c < OUT * 16; c += 256) {
        const int nn = c >> 4, q = c & 15;
        f16x8 w = *(const f16x8*)&Wt[nn * 128 + q * 8];
        *(f16x8*)&Ws[(size_t)((nn << 4) + (q ^ (nn & 15))) * 8] = w;
    }
    __syncthreads();

    constexpr int NT = OUT / 16;
    const int lane = t & 63, wave = t >> 6;
    const int m = lane & 15, quad = lane >> 4;

    f32x4 acc[NT];
    #pragma unroll
    for (int i = 0; i < NT; ++i) acc[i] = (f32x4){0.f, 0.f, 0.f, 0.f};

    #pragma unroll
    for (int s = 0; s < 4; ++s) {
        const int qa = s * 4 + quad;
        f16x8 a = *(const f16x8*)&Xs[(size_t)(((wave * 16 + m) << 4) + (qa ^ m)) * 8];
        #pragma unroll
        for (int tt = 0; tt < NT; ++tt) {
            f16x8 b = *(const f16x8*)&Ws[(size_t)(((tt * 16 + m) << 4) + (qa ^ m)) * 8];
            acc[tt] = __builtin_amdgcn_mfma_f32_16x16x32_f16(a, b, acc[tt], 0, 0, 0);
        }
    }

    // epilogue: C/D layout col=lane&15 (within tile), row=quad*4+reg
    #pragma unroll
    for (int i = 0; i < 4; ++i) {
        const int gr = row0 + wave * 16 + quad * 4 + i;
        if (gr < n) {
            const float dw = dinv[gr];
            #pragma unroll
            for (int tt = 0; tt < NT; ++tt)
                Yh[(size_t)gr * OUT + tt * 16 + m] = __float2half(acc[tt][i] * dw);
        }
    }
}

// ---------------- gather: out[c,:] = dinv[c] * (hs[c,:] + sum_in hs[src,:]) ----------------

template <int F>
__global__ void gather_kernel(const __half* __restrict__ hs, const float* __restrict__ dinv,
                              const int* __restrict__ ptr, const int* __restrict__ csr,
                              float* __restrict__ out, int n) {
    const int lane = threadIdx.x & 63;
    const int c = (blockIdx.x * blockDim.x + threadIdx.x) >> 6;
    if (c >= n) return;
    const int beg = ptr[c], end = ptr[c + 1];
    const float w = dinv[c];
    const float2* hq = (const float2*)hs;

    auto cvt = [](float2 raw) {
        __half2 ha = *(__half2*)&raw.x;
        __half2 hb = *(__half2*)&raw.y;
        float2 fa = __half22float2(ha);
        float2 fb = __half22float2(hb);
        return make_float4(fa.x, fa.y, fb.x, fb.y);
    };

    if (F == 128) {
        const int half = lane >> 5;
        const int l    = lane & 31;
        float4 acc = make_float4(0.f, 0.f, 0.f, 0.f);
        if (half == 0) acc = cvt(hq[(size_t)c * 32 + l]);
        int j = beg + half;
        for (; j + 6 < end; j += 8) {
            int s0 = csr[j], s1 = csr[j + 2], s2 = csr[j + 4], s3 = csr[j + 6];
            float4 v0 = cvt(hq[(size_t)s0 * 32 + l]);
            float4 v1 = cvt(hq[(size_t)s1 * 32 + l]);
            float4 v2 = cvt(hq[(size_t)s2 * 32 + l]);
            float4 v3 = cvt(hq[(size_t)s3 * 32 + l]);
            acc.x += v0.x + v1.x + v2.x + v3.x;
            acc.y += v0.y + v1.y + v2.y + v3.y;
            acc.z += v0.z + v1.z + v2.z + v3.z;
            acc.w += v0.w + v1.w + v2.w + v3.w;
        }
        for (; j < end; j += 2) {
            float4 v = cvt(hq[(size_t)csr[j] * 32 + l]);
            acc.x += v.x; acc.y += v.y; acc.z += v.z; acc.w += v.w;
        }
        acc.x += __shfl(acc.x, lane ^ 32);
        acc.y += __shfl(acc.y, lane ^ 32);
        acc.z += __shfl(acc.z, lane ^ 32);
        acc.w += __shfl(acc.w, lane ^ 32);
        if (half == 0) {
            float4 o = make_float4(w * acc.x, w * acc.y, w * acc.z, w * acc.w);
            ((float4*)out)[(size_t)c * 32 + l] = o;
        }
    } else {     // F == 64
        const int q = lane >> 4;
        const int l = lane & 15;
        float4 acc = make_float4(0.f, 0.f, 0.f, 0.f);
        if (q == 0) acc = cvt(hq[(size_t)c * 16 + l]);
        int j = beg + q;
        for (; j + 12 < end; j += 16) {
            int s0 = csr[j], s1 = csr[j + 4], s2 = csr[j + 8], s3 = csr[j + 12];
            float4 v0 = cvt(hq[(size_t)s0 * 16 + l]);
            float4 v1 = cvt(hq[(size_t)s1 * 16 + l]);
            float4 v2 = cvt(hq[(size_t)s2 * 16 + l]);
            float4 v3 = cvt(hq[(size_t)s3 * 16 + l]);
            acc.x += v0.x + v1.x + v2.x + v3.x;
            acc.y += v0.y + v1.y + v2.y + v3.y;
            acc.z += v0.z + v1.z + v2.z + v3.z;
            acc.w += v0.w + v1.w + v2.w + v3.w;
        }
        for (; j < end; j += 4) {
            float4 v = cvt(hq[(size_t)csr[j] * 16 + l]);
            acc.x += v.x; acc.y += v.y; acc.z += v.z; acc.w += v.w;
        }
        acc.x += __shfl(acc.x, lane ^ 16);
        acc.y += __shfl(acc.y, lane ^ 16);
        acc.z += __shfl(acc.z, lane ^ 16);
        acc.w += __shfl(acc.w, lane ^ 16);
        acc.x += __shfl(acc.x, lane ^ 32);
        acc.y += __shfl(acc.y, lane ^ 32);
        acc.z += __shfl(acc.z, lane ^ 32);
        acc.w += __shfl(acc.w, lane ^ 32);
        if (q == 0) {
            float4 o = make_float4(w * acc.x, w * acc.y, w * acc.z, w * acc.w);
            ((float4*)out)[(size_t)c * 16 + l] = o;
        }
    }
}

// ---------------- fused mean-pool + MLP head ----------------

__global__ void pool_mlp_kernel(const float* __restrict__ h, const float* __restrict__ b3,
                                const int* __restrict__ batch,
                                const float* __restrict__ Wf1, const float* __restrict__ bf1,
                                const float* __restrict__ Wf2, const float* __restrict__ bf2,
                                float* __restrict__ out, int n) {
    const int g = blockIdx.x;
    const int t = threadIdx.x;

    auto lb = [&](int v) {
        int lo = 0, hi = n;
        while (lo < hi) { int mid = (lo + hi) >> 1; if (batch[mid] < v) lo = mid + 1; else hi = mid; }
        return lo;
    };
    const int start = lb(g);
    const int end   = lb(g + 1);

    __shared__ float part[4][64];
    __shared__ float pooled[64];
    __shared__ float hid[32];

    const int f = t & 63, sub = t >> 6;
    const float bias = b3[f];
    float acc = 0.f;
    for (int i = start + sub; i < end; i += 4)
        acc += fmaxf(h[(size_t)i * 64 + f] + bias, 0.f);
    part[sub][f] = acc;
    __syncthreads();

    if (t < 64) {
        float s = part[0][t] + part[1][t] + part[2][t] + part[3][t];
        int cnt = end - start;
        pooled[t] = s / (float)(cnt > 0 ? cnt : 1);
    }
    __syncthreads();

    if (t < 32) {
        float a = bf1[t];
        #pragma unroll
        for (int k = 0; k < 64; ++k) a += pooled[k] * Wf1[k * 32 + t];
        hid[t] = fmaxf(a, 0.f);
    }
    __syncthreads();

    if (t < 10) {
        float a = bf2[t];
        #pragma unroll
        for (int k = 0; k < 32; ++k) a += hid[k] * Wf2[k * 10 + t];
        out[g * 10 + t] = a;
    }
}

// ---------------- launcher ----------------

extern "C" void kernel_launch(void* const* d_in, const int* in_sizes, int n_in,
                              void* d_out, int out_size, void* d_ws, size_t ws_size,
                              hipStream_t stream) {
    const float* x     = (const float*)d_in[0];
    const int*   edge  = (const int*)  d_in[1];
    const int*   batch = (const int*)  d_in[2];
    const float* W1    = (const float*)d_in[3];
    const float* b1    = (const float*)d_in[4];
    const float* W2    = (const float*)d_in[5];
    const float* b2    = (const float*)d_in[6];
    const float* W3    = (const float*)d_in[7];
    const float* b3    = (const float*)d_in[8];
    const float* Wf1   = (const float*)d_in[9];
    const float* bf1   = (const float*)d_in[10];
    const float* Wf2   = (const float*)d_in[11];
    const float* bf2   = (const float*)d_in[12];
    float* out = (float*)d_out;

    const int E = in_sizes[1] / 2;     // 800000
    const int n = in_sizes[2];         // 50000
    const int* row = edge;
    const int* col = edge + E;

    const int nblk = (n + 1023) / 1024;                    // scan chunks (49)
    const int colsPerGroup = (n + 7) / 8;                  // 6250

    const size_t n_pad = ((size_t)n + 64) & ~(size_t)63;   // >= n+1, 64-aligned
    char* wsb = (char*)d_ws;
    int*    cnt  = (int*)wsb;                    wsb += n_pad * 4;   // reused as cursor
    int*    ptr  = (int*)wsb;                    wsb += n_pad * 4;
    float*  dinv = (float*)wsb;                  wsb += n_pad * 4;
    int*    bsum = (int*)wsb;                    wsb += 256 * 4;
    int*    csr  = (int*)wsb;                    wsb += (((size_t)E + 63) & ~(size_t)63) * 4;
    __half* Wt1  = (__half*)wsb;                 wsb += 16384 * 2;
    __half* Wt2  = (__half*)wsb;                 wsb += 16384 * 2;
    __half* Wt3  = (__half*)wsb;                 wsb += 8192 * 2;
    __half* bufA = (__half*)wsb;                 wsb += (size_t)n * 128 * 2;   // fp16 hs
    float*  bufB = (float*)wsb;

    // ---- weight prep + CSR build (once, reused for all 3 layers) ----
    prep_w<<<160, 256, 0, stream>>>(W1, W2, W3, Wt1, Wt2, Wt3);
    hipMemsetAsync(cnt, 0, (size_t)n * 4, stream);
    deg_kernel<<<1024, 256, 0, stream>>>(col, cnt, E, colsPerGroup);
    scan_part1<<<nblk, 256, 0, stream>>>(cnt, bsum, n);
    scan_part2<<<1, 256, 0, stream>>>(bsum, nblk);
    scan_part3<<<nblk, 256, 0, stream>>>(cnt, bsum, ptr, cnt, dinv, n, E);  // cursor aliases cnt
    fill_kernel<<<1024, 256, 0, stream>>>(row, col, cnt, csr, E, colsPerGroup);

    const int ggemm = (n + 63) / 64;   // 64 rows per block
    const int gath_grid = (n * 64 + 255) / 256;            // one wave per node

    // layer 1
    gemm_mfma<128><<<ggemm, 256, 0, stream>>>(x, Wt1, nullptr, dinv, bufA, n);
    gather_kernel<128><<<gath_grid, 256, 0, stream>>>(bufA, dinv, ptr, csr, bufB, n);
    // layer 2
    gemm_mfma<128><<<ggemm, 256, 0, stream>>>(bufB, Wt2, b1, dinv, bufA, n);
    gather_kernel<128><<<gath_grid, 256, 0, stream>>>(bufA, dinv, ptr, csr, bufB, n);
    // layer 3 (64-wide)
    gemm_mfma<64><<<ggemm, 256, 0, stream>>>(bufB, Wt3, b2, dinv, bufA, n);
    gather_kernel<64><<<gath_grid, 256, 0, stream>>>(bufA, dinv, ptr, csr, bufB, n);

    // fused relu(+b3) -> mean pool -> MLP
    pool_mlp_kernel<<<NGRAPH, 256, 0, stream>>>(bufB, b3, batch, Wf1, bf1, Wf2, bf2, out, n);
}

// Round 9
// 341.074 us; speedup vs baseline: 5.2798x; 1.0130x over previous
//
#include <hip/hip_runtime.h>
#include <hip/hip_fp16.h>

// GCN: 3x (GEMM -> normalized adjacency aggregate) + mean-pool + MLP.
// R2: atomic scatter -> CSR + gather.  R3: hierarchical scan.
// R4: register-tiled GEMM.  R5: MLP probe -> gather is LLC-fill-BW bound.
// R6: hs fp16. 470->419.  R7: col-partitioned fill. ->409.
// R8: fp16 MFMA GEMM (XOR-swizzled LDS). ->345.
// R9: pool/MLP head split: single-wave-per-graph pool_mlp (44us, 3% occupancy)
//     -> full-device pool_sum (register accum + boundary-flush atomics, lane=feat)
//     + tiny mlp_kernel. pooled[] zeroed in scan_part2's idle cycles.
//   out[c] = dinv[c] * ( hs[c] + sum_{(r->c)} hs[r] ),  hs = (X@W) * dinv[row]

#define NGRAPH 100

typedef _Float16 f16x8 __attribute__((ext_vector_type(8)));
typedef float f32x4 __attribute__((ext_vector_type(4)));

// ---------------- degree histogram (int), col-partitioned ----------------

__global__ void deg_kernel(const int* __restrict__ col, int* __restrict__ cnt,
                           int E, int colsPerGroup) {
    const int g  = blockIdx.x & 7;
    const int gb = blockIdx.x >> 3;
    const int nb = gridDim.x >> 3;
    const int lo = g * colsPerGroup, hi = lo + colsPerGroup;
    for (int e = gb * 256 + threadIdx.x; e < E; e += nb * 256) {
        int c = col[e];
        if (c >= lo && c < hi) atomicAdd(&cnt[c], 1);
    }
}

// ---------------- hierarchical exclusive scan: cnt[0..n) -> ptr[0..n] ----------------

__global__ __launch_bounds__(256) void scan_part1(const int* __restrict__ cnt,
                                                  int* __restrict__ bsum, int n) {
    __shared__ int ts[256];
    const int b = blockIdx.x, t = threadIdx.x;
    const int base = b * 1024 + t * 4;
    int s = 0;
    if (base + 3 < n) { int4 q = *(const int4*)&cnt[base]; s = q.x + q.y + q.z + q.w; }
    else { for (int i = 0; i < 4; ++i) if (base + i < n) s += cnt[base + i]; }
    ts[t] = s;
    __syncthreads();
    for (int off = 128; off > 0; off >>= 1) {
        if (t < off) ts[t] += ts[t + off];
        __syncthreads();
    }
    if (t == 0) bsum[b] = ts[0];
}

// also zeroes pooled[NGRAPH*64] (runs before pool_sum; free ride, no extra dispatch)
__global__ __launch_bounds__(256) void scan_part2(int* __restrict__ bsum, int nblk,
                                                  float* __restrict__ pooled) {
    __shared__ int ts[256];
    const int t = threadIdx.x;
    for (int i = t; i < NGRAPH * 64; i += 256) pooled[i] = 0.0f;
    int v = (t < nblk) ? bsum[t] : 0;
    ts[t] = v;
    __syncthreads();
    for (int off = 1; off < 256; off <<= 1) {
        int x = (t >= off) ? ts[t - off] : 0;
        __syncthreads();
        ts[t] += x;
        __syncthreads();
    }
    if (t < nblk) bsum[t] = ts[t] - v;   // exclusive
}

__global__ __launch_bounds__(256) void scan_part3(const int* __restrict__ cnt,
                                                  const int* __restrict__ bsum,
                                                  int* __restrict__ ptr,
                                                  int* __restrict__ cursor,
                                                  float* __restrict__ dinv,
                                                  int n, int E) {
    __shared__ int ts[256];
    const int b = blockIdx.x, t = threadIdx.x;
    const int base = b * 1024 + t * 4;
    int v0 = 0, v1 = 0, v2 = 0, v3 = 0;
    if (base + 3 < n) {
        int4 q = *(const int4*)&cnt[base]; v0 = q.x; v1 = q.y; v2 = q.z; v3 = q.w;
    } else {
        if (base     < n) v0 = cnt[base];
        if (base + 1 < n) v1 = cnt[base + 1];
        if (base + 2 < n) v2 = cnt[base + 2];
        if (base + 3 < n) v3 = cnt[base + 3];
    }
    const int s = v0 + v1 + v2 + v3;
    ts[t] = s;
    __syncthreads();
    for (int off = 1; off < 256; off <<= 1) {
        int x = (t >= off) ? ts[t - off] : 0;
        __syncthreads();
        ts[t] += x;
        __syncthreads();
    }
    int e0 = ts[t] - s + bsum[b];
    int e1 = e0 + v0, e2 = e1 + v1, e3 = e2 + v2;
    if (base < n) {
        ptr[base] = e0; cursor[base] = e0;
        dinv[base] = 1.0f / sqrtf((float)(v0 + 1));
    }
    if (base + 1 < n) {
        ptr[base + 1] = e1; cursor[base + 1] = e1;
        dinv[base + 1] = 1.0f / sqrtf((float)(v1 + 1));
    }
    if (base + 2 < n) {
        ptr[base + 2] = e2; cursor[base + 2] = e2;
        dinv[base + 2] = 1.0f / sqrtf((float)(v2 + 1));
    }
    if (base + 3 < n) {
        ptr[base + 3] = e3; cursor[base + 3] = e3;
        dinv[base + 3] = 1.0f / sqrtf((float)(v3 + 1));
    }
    if (b == (int)gridDim.x - 1 && t == 255) ptr[n] = E;
}

// ---------------- CSR fill, col-partitioned ----------------

__global__ void fill_kernel(const int* __restrict__ row, const int* __restrict__ col,
                            int* __restrict__ cursor, int* __restrict__ csr,
                            int E, int colsPerGroup) {
    const int g  = blockIdx.x & 7;
    const int gb = blockIdx.x >> 3;
    const int nb = gridDim.x >> 3;
    const int lo = g * colsPerGroup, hi = lo + colsPerGroup;
    for (int e = gb * 256 + threadIdx.x; e < E; e += nb * 256) {
        int c = col[e];
        if (c >= lo && c < hi) {
            int pos = atomicAdd(&cursor[c], 1);
            csr[pos] = row[e];
        }
    }
}

// ---------------- W prep: Wt[n][k] = (half)W[k][n] ----------------

__global__ void prep_w(const float* __restrict__ W1, const float* __restrict__ W2,
                       const float* __restrict__ W3,
                       __half* __restrict__ Wt1, __half* __restrict__ Wt2,
                       __half* __restrict__ Wt3) {
    int idx = blockIdx.x * 256 + threadIdx.x;
    if (idx < 16384) {
        int nn = idx >> 7, k = idx & 127;
        Wt1[idx] = __float2half(W1[k * 128 + nn]);
    } else if (idx < 32768) {
        int j = idx - 16384;
        int nn = j >> 7, k = j & 127;
        Wt2[j] = __float2half(W2[k * 128 + nn]);
    } else if (idx < 40960) {
        int j = idx - 32768;
        int nn = j >> 7, k = j & 127;
        Wt3[j] = __float2half(W3[k * 64 + nn]);
    }
}

// ---------------- MFMA GEMM: Yh[n,OUT](fp16) = relu?(X + b) @ W * dinv[row] ----------

template <int OUT>
__global__ __launch_bounds__(256) void gemm_mfma(const float* __restrict__ X,
                                                 const __half* __restrict__ Wt,
                                                 const float* __restrict__ bias_in,
                                                 const float* __restrict__ dinv,
                                                 __half* __restrict__ Yh, int n) {
    __shared__ _Float16 Xs[64 * 128];
    __shared__ _Float16 Ws[OUT * 128];
    __shared__ float bs[128];

    const int t = threadIdx.x;
    if (t < 128) bs[t] = (bias_in != nullptr) ? bias_in[t] : 0.0f;
    __syncthreads();

    const int row0 = blockIdx.x * 64;
    const bool do_relu = (bias_in != nullptr);

    for (int c = t; c < 64 * 16; c += 256) {
        const int r = c >> 4, q = c & 15;
        const int gr = row0 + r;
        float4 va = make_float4(0.f, 0.f, 0.f, 0.f), vb = va;
        if (gr < n) {
            va = *(const float4*)&X[(size_t)gr * 128 + q * 8];
            vb = *(const float4*)&X[(size_t)gr * 128 + q * 8 + 4];
        }
        if (do_relu) {
            const int k = q * 8;
            va.x = fmaxf(va.x + bs[k + 0], 0.f);
            va.y = fmaxf(va.y + bs[k + 1], 0.f);
            va.z = fmaxf(va.z + bs[k + 2], 0.f);
            va.w = fmaxf(va.w + bs[k + 3], 0.f);
            vb.x = fmaxf(vb.x + bs[k + 4], 0.f);
            vb.y = fmaxf(vb.y + bs[k + 5], 0.f);
            vb.z = fmaxf(vb.z + bs[k + 6], 0.f);
            vb.w = fmaxf(vb.w + bs[k + 7], 0.f);
        }
        f16x8 hv;
        hv[0] = (_Float16)va.x; hv[1] = (_Float16)va.y;
        hv[2] = (_Float16)va.z; hv[3] = (_Float16)va.w;
        hv[4] = (_Float16)vb.x; hv[5] = (_Float16)vb.y;
        hv[6] = (_Float16)vb.z; hv[7] = (_Float16)vb.w;
        *(f16x8*)&Xs[(size_t)((r << 4) + (q ^ (r & 15))) * 8] = hv;
    }
    for (int c = t; c < OUT * 16; c += 256) {
        const int nn = c >> 4, q = c & 15;
        f16x8 w = *(const f16x8*)&Wt[nn * 128 + q * 8];
        *(f16x8*)&Ws[(size_t)((nn << 4) + (q ^ (nn & 15))) * 8] = w;
    }
    __syncthreads();

    constexpr int NT = OUT / 16;
    const int lane = t & 63, wave = t >> 6;
    const int m = lane & 15, quad = lane >> 4;

    f32x4 acc[NT];
    #pragma unroll
    for (int i = 0; i < NT; ++i) acc[i] = (f32x4){0.f, 0.f, 0.f, 0.f};

    #pragma unroll
    for (int s = 0; s < 4; ++s) {
        const int qa = s * 4 + quad;
        f16x8 a = *(const f16x8*)&Xs[(size_t)(((wave * 16 + m) << 4) + (qa ^ m)) * 8];
        #pragma unroll
        for (int tt = 0; tt < NT; ++tt) {
            f16x8 b = *(const f16x8*)&Ws[(size_t)(((tt * 16 + m) << 4) + (qa ^ m)) * 8];
            acc[tt] = __builtin_amdgcn_mfma_f32_16x16x32_f16(a, b, acc[tt], 0, 0, 0);
        }
    }

    #pragma unroll
    for (int i = 0; i < 4; ++i) {
        const int gr = row0 + wave * 16 + quad * 4 + i;
        if (gr < n) {
            const float dw = dinv[gr];
            #pragma unroll
            for (int tt = 0; tt < NT; ++tt)
                Yh[(size_t)gr * OUT + tt * 16 + m] = __float2half(acc[tt][i] * dw);
        }
    }
}

// ---------------- gather: out[c,:] = dinv[c] * (hs[c,:] + sum_in hs[src,:]) ----------------

template <int F>
__global__ void gather_kernel(const __half* __restrict__ hs, const float* __restrict__ dinv,
                              const int* __restrict__ ptr, const int* __restrict__ csr,
                              float* __restrict__ out, int n) {
    const int lane = threadIdx.x & 63;
    const int c = (blockIdx.x * blockDim.x + threadIdx.x) >> 6;
    if (c >= n) return;
    const int beg = ptr[c], end = ptr[c + 1];
    const float w = dinv[c];
    const float2* hq = (const float2*)hs;

    auto cvt = [](float2 raw) {
        __half2 ha = *(__half2*)&raw.x;
        __half2 hb = *(__half2*)&raw.y;
        float2 fa = __half22float2(ha);
        float2 fb = __half22float2(hb);
        return make_float4(fa.x, fa.y, fb.x, fb.y);
    };

    if (F == 128) {
        const int half = lane >> 5;
        const int l    = lane & 31;
        float4 acc = make_float4(0.f, 0.f, 0.f, 0.f);
        if (half == 0) acc = cvt(hq[(size_t)c * 32 + l]);
        int j = beg + half;
        for (; j + 6 < end; j += 8) {
            int s0 = csr[j], s1 = csr[j + 2], s2 = csr[j + 4], s3 = csr[j + 6];
            float4 v0 = cvt(hq[(size_t)s0 * 32 + l]);
            float4 v1 = cvt(hq[(size_t)s1 * 32 + l]);
            float4 v2 = cvt(hq[(size_t)s2 * 32 + l]);
            float4 v3 = cvt(hq[(size_t)s3 * 32 + l]);
            acc.x += v0.x + v1.x + v2.x + v3.x;
            acc.y += v0.y + v1.y + v2.y + v3.y;
            acc.z += v0.z + v1.z + v2.z + v3.z;
            acc.w += v0.w + v1.w + v2.w + v3.w;
        }
        for (; j < end; j += 2) {
            float4 v = cvt(hq[(size_t)csr[j] * 32 + l]);
            acc.x += v.x; acc.y += v.y; acc.z += v.z; acc.w += v.w;
        }
        acc.x += __shfl(acc.x, lane ^ 32);
        acc.y += __shfl(acc.y, lane ^ 32);
        acc.z += __shfl(acc.z, lane ^ 32);
        acc.w += __shfl(acc.w, lane ^ 32);
        if (half == 0) {
            float4 o = make_float4(w * acc.x, w * acc.y, w * acc.z, w * acc.w);
            ((float4*)out)[(size_t)c * 32 + l] = o;
        }
    } else {     // F == 64
        const int q = lane >> 4;
        const int l = lane & 15;
        float4 acc = make_float4(0.f, 0.f, 0.f, 0.f);
        if (q == 0) acc = cvt(hq[(size_t)c * 16 + l]);
        int j = beg + q;
        for (; j + 12 < end; j += 16) {
            int s0 = csr[j], s1 = csr[j + 4], s2 = csr[j + 8], s3 = csr[j + 12];
            float4 v0 = cvt(hq[(size_t)s0 * 16 + l]);
            float4 v1 = cvt(hq[(size_t)s1 * 16 + l]);
            float4 v2 = cvt(hq[(size_t)s2 * 16 + l]);
            float4 v3 = cvt(hq[(size_t)s3 * 16 + l]);
            acc.x += v0.x + v1.x + v2.x + v3.x;
            acc.y += v0.y + v1.y + v2.y + v3.y;
            acc.z += v0.z + v1.z + v2.z + v3.z;
            acc.w += v0.w + v1.w + v2.w + v3.w;
        }
        for (; j < end; j += 4) {
            float4 v = cvt(hq[(size_t)csr[j] * 16 + l]);
            acc.x += v.x; acc.y += v.y; acc.z += v.z; acc.w += v.w;
        }
        acc.x += __shfl(acc.x, lane ^ 16);
        acc.y += __shfl(acc.y, lane ^ 16);
        acc.z += __shfl(acc.z, lane ^ 16);
        acc.w += __shfl(acc.w, lane ^ 16);
        acc.x += __shfl(acc.x, lane ^ 32);
        acc.y += __shfl(acc.y, lane ^ 32);
        acc.z += __shfl(acc.z, lane ^ 32);
        acc.w += __shfl(acc.w, lane ^ 32);
        if (q == 0) {
            float4 o = make_float4(w * acc.x, w * acc.y, w * acc.z, w * acc.w);
            ((float4*)out)[(size_t)c * 16 + l] = o;
        }
    }
}

// ---------------- pool phase A: pooled[g][f] += relu(h[i][f]+b3[f]) ----------------
// Grid-stride waves; lane = feature; batch sorted -> register accumulate,
// atomic flush only at graph boundaries (wave-uniform branch).

__global__ __launch_bounds__(256) void pool_sum(const float* __restrict__ h,
                                                const float* __restrict__ b3,
                                                const int* __restrict__ batch,
                                                float* __restrict__ pooled, int n) {
    const int lane  = threadIdx.x & 63;
    const int wave  = (blockIdx.x * blockDim.x + threadIdx.x) >> 6;
    const int nwav  = (gridDim.x * blockDim.x) >> 6;
    const int chunk = (n + nwav - 1) / nwav;
    const int beg = wave * chunk;
    const int end = min(beg + chunk, n);
    if (beg >= end) return;
    const float bias = b3[lane];
    int curg = batch[beg];
    float acc = 0.f;
    for (int i = beg; i < end; ++i) {
        int g = batch[i];                      // wave-uniform
        if (g != curg) {
            atomicAdd(&pooled[curg * 64 + lane], acc);
            acc = 0.f; curg = g;
        }
        acc += fmaxf(h[(size_t)i * 64 + lane] + bias, 0.f);
    }
    atomicAdd(&pooled[curg * 64 + lane], acc);
}

// ---------------- pool phase B: mean + 64->32->10 MLP, one 64-thr block/graph ------

__global__ __launch_bounds__(64) void mlp_kernel(const float* __restrict__ pooled,
                                                 const int* __restrict__ batch,
                                                 const float* __restrict__ Wf1,
                                                 const float* __restrict__ bf1,
                                                 const float* __restrict__ Wf2,
                                                 const float* __restrict__ bf2,
                                                 float* __restrict__ out, int n) {
    const int g = blockIdx.x;
    const int t = threadIdx.x;

    auto lb = [&](int v) {
        int lo = 0, hi = n;
        while (lo < hi) { int mid = (lo + hi) >> 1; if (batch[mid] < v) lo = mid + 1; else hi = mid; }
        return lo;
    };
    const int cnt = lb(g + 1) - lb(g);

    __shared__ float pm[64];
    __shared__ float hid[32];

    pm[t] = pooled[g * 64 + t] / (float)(cnt > 0 ? cnt : 1);
    __syncthreads();

    if (t < 32) {
        float a = bf1[t];
        #pragma unroll
        for (int k = 0; k < 64; ++k) a += pm[k] * Wf1[k * 32 + t];
        hid[t] = fmaxf(a, 0.f);
    }
    __syncthreads();

    if (t < 10) {
        float a = bf2[t];
        #pragma unroll
        for (int k = 0; k < 32; ++k) a += hid[k] * Wf2[k * 10 + t];
        out[g * 10 + t] = a;
    }
}

// ---------------- launcher ----------------

extern "C" void kernel_launch(void* const* d_in, const int* in_sizes, int n_in,
                              void* d_out, int out_size, void* d_ws, size_t ws_size,
                              hipStream_t stream) {
    const float* x     = (const float*)d_in[0];
    const int*   edge  = (const int*)  d_in[1];
    const int*   batch = (const int*)  d_in[2];
    const float* W1    = (const float*)d_in[3];
    const float* b1    = (const float*)d_in[4];
    const float* W2    = (const float*)d_in[5];
    const float* b2    = (const float*)d_in[6];
    const float* W3    = (const float*)d_in[7];
    const float* b3    = (const float*)d_in[8];
    const float* Wf1   = (const float*)d_in[9];
    const float* bf1   = (const float*)d_in[10];
    const float* Wf2   = (const float*)d_in[11];
    const float* bf2   = (const float*)d_in[12];
    float* out = (float*)d_out;

    const int E = in_sizes[1] / 2;     // 800000
    const int n = in_sizes[2];         // 50000
    const int* row = edge;
    const int* col = edge + E;

    const int nblk = (n + 1023) / 1024;                    // scan chunks (49)
    const int colsPerGroup = (n + 7) / 8;                  // 6250

    const size_t n_pad = ((size_t)n + 64) & ~(size_t)63;   // >= n+1, 64-aligned
    char* wsb = (char*)d_ws;
    int*    cnt    = (int*)wsb;                  wsb += n_pad * 4;   // reused as cursor
    int*    ptr    = (int*)wsb;                  wsb += n_pad * 4;
    float*  dinv   = (float*)wsb;                wsb += n_pad * 4;
    int*    bsum   = (int*)wsb;                  wsb += 256 * 4;
    float*  pooled = (float*)wsb;                wsb += NGRAPH * 64 * 4;
    int*    csr    = (int*)wsb;                  wsb += (((size_t)E + 63) & ~(size_t)63) * 4;
    __half* Wt1    = (__half*)wsb;               wsb += 16384 * 2;
    __half* Wt2    = (__half*)wsb;               wsb += 16384 * 2;
    __half* Wt3    = (__half*)wsb;               wsb += 8192 * 2;
    __half* bufA   = (__half*)wsb;               wsb += (size_t)n * 128 * 2;   // fp16 hs
    float*  bufB   = (float*)wsb;

    // ---- weight prep + CSR build (once, reused for all 3 layers) ----
    prep_w<<<160, 256, 0, stream>>>(W1, W2, W3, Wt1, Wt2, Wt3);
    hipMemsetAsync(cnt, 0, (size_t)n * 4, stream);
    deg_kernel<<<1024, 256, 0, stream>>>(col, cnt, E, colsPerGroup);
    scan_part1<<<nblk, 256, 0, stream>>>(cnt, bsum, n);
    scan_part2<<<1, 256, 0, stream>>>(bsum, nblk, pooled);   // also zeroes pooled
    scan_part3<<<nblk, 256, 0, stream>>>(cnt, bsum, ptr, cnt, dinv, n, E);  // cursor aliases cnt
    fill_kernel<<<1024, 256, 0, stream>>>(row, col, cnt, csr, E, colsPerGroup);

    const int ggemm = (n + 63) / 64;   // 64 rows per block
    const int gath_grid = (n * 64 + 255) / 256;            // one wave per node

    // layer 1
    gemm_mfma<128><<<ggemm, 256, 0, stream>>>(x, Wt1, nullptr, dinv, bufA, n);
    gather_kernel<128><<<gath_grid, 256, 0, stream>>>(bufA, dinv, ptr, csr, bufB, n);
    // layer 2
    gemm_mfma<128><<<ggemm, 256, 0, stream>>>(bufB, Wt2, b1, dinv, bufA, n);
    gather_kernel<128><<<gath_grid, 256, 0, stream>>>(bufA, dinv, ptr, csr, bufB, n);
    // layer 3 (64-wide)
    gemm_mfma<64><<<ggemm, 256, 0, stream>>>(bufB, Wt3, b2, dinv, bufA, n);
    gather_kernel<64><<<gath_grid, 256, 0, stream>>>(bufA, dinv, ptr, csr, bufB, n);

    // head: relu(+b3) -> mean pool (2-phase) -> MLP
    pool_sum<<<200, 256, 0, stream>>>(bufB, b3, batch, pooled, n);
    mlp_kernel<<<NGRAPH, 64, 0, stream>>>(pooled, batch, Wf1, bf1, Wf2, bf2, out, n);
}